// Round 7
// baseline (801.787 us; speedup 1.0000x reference)
//
#include <hip/hip_runtime.h>

typedef unsigned short u16;
typedef unsigned int   u32;
typedef __attribute__((ext_vector_type(8))) short s16x8;
typedef __attribute__((ext_vector_type(4))) float f32x4;
typedef __attribute__((ext_vector_type(4), aligned(4))) float f32x4u;  // 4B-aligned vec load
typedef __attribute__((ext_vector_type(4))) u32   u32x4;
typedef __attribute__((ext_vector_type(4))) u16   u16x4;

#define NPIX 16641   /* 129*129 */
#define HP   131     /* padded spatial dim (convs) */
#define FPY  135     /* NHWC padded spatial dim (svconv: 129 + 3+3) */

// ---- workspace layout (bytes) ----
// region A (two lifetimes):
//   phase 1: U [4][131][131][128] bf16 @ 0 (17.6M), S1 [2][131][131][512] bf16 @ 17572864 (35.1M)
//   phase 2 (after conv2): Fp [2][135][135][256] f32 NHWC @ 0 (37,324,800)
//                          P  [2][16641][52] f32        @ 37601280 (6,922,656)
// Wt1  : [9][256][128] bf16  @ 52718592   (589,824)
// Wt2  : [9][256][512] bf16  @ 53308416   (2,359,296)
// out2a: [2*16641][256] bf16 @ 55667712   (17,040,384)  split-K half 0 (pre-relu, +bias)
// out2b: [2*16641][256] bf16 @ 72708096   (17,040,384)  split-K half 1
// w3t  : [256][49] f32       @ 89748480   (50,176)
// total required: 89,798,656 B

__device__ __forceinline__ u16 f2bf(float f) {
    u32 b = __builtin_bit_cast(u32, f);
    return (u16)((b + 0x7fffu + ((b >> 16) & 1u)) >> 16);
}
__device__ __forceinline__ float bf2f(u16 u) {
    return __builtin_bit_cast(float, ((u32)u) << 16);
}

// async global->LDS, 16B per lane; LDS dest wave-uniform base, lane l -> +16*l
__device__ __forceinline__ void async_cp16(const void* g, void* l) {
    __builtin_amdgcn_global_load_lds(
        (const __attribute__((address_space(1))) u32*)g,
        (__attribute__((address_space(3))) u32*)l, 16, 0, 0);
}

// zero only the 1-pixel pad ring of U (4 imgs, C=128) and S1 (2 imgs, C=512).
__global__ __launch_bounds__(256) void zero_border(u16* __restrict__ U,
                                                   u16* __restrict__ S1) {
    const int plane = blockIdx.y;           // 0..3: U, 4..5: S1
    const bool isU = plane < 4;
    const int C = isU ? 128 : 512;
    const int cpp = C / 8;
    int e = blockIdx.x * 256 + threadIdx.x;
    if (e >= 520 * cpp) return;
    int pix = e / cpp, ch = e - pix * cpp;
    int r, c;
    if (pix < 131)      { r = 0;   c = pix; }
    else if (pix < 262) { r = 130; c = pix - 131; }
    else { int j = pix - 262; r = 1 + (j >> 1); c = (j & 1) ? 130 : 0; }
    int img = isU ? plane : (plane - 4);
    u16* base = (isU ? U : S1) + ((long)(img * HP + r) * HP + c) * C + ch * 8;
    u32x4 z = {0u, 0u, 0u, 0u};
    *(u32x4*)base = z;
}

// transform weights: Wt[tap][co][ci] (bf16), w3t[c][t] (f32)
__global__ __launch_bounds__(256) void prep_weights(
        const float* __restrict__ wr, const float* __restrict__ w2,
        const float* __restrict__ w3,
        u16* __restrict__ Wt1, u16* __restrict__ Wt2, float* __restrict__ w3t) {
    int i = blockIdx.x * 256 + threadIdx.x;
    if (i < 294912) {
        int tap = i / 32768, r = i & 32767;
        int co = r >> 7, ci = r & 127;
        Wt1[i] = f2bf(wr[(co * 128 + ci) * 9 + tap]);
    } else if (i < 1474560) {
        int j = i - 294912;
        int tap = j / 131072, r = j & 131071;
        int co = r >> 9, ci = r & 511;
        Wt2[j] = f2bf(w2[(co * 512 + ci) * 9 + tap]);
    } else if (i < 1487104) {
        int j = i - 1474560;
        int c = j / 49, t = j - c * 49;
        w3t[j] = w3[t * 256 + c];
    }
}

// bilinear upsample 33x33 -> 129x129, write padded NHWC bf16
__global__ __launch_bounds__(256) void upsample(
        const float* __restrict__ cur, const float* __restrict__ key,
        u16* __restrict__ U) {
    __shared__ float rows[2][128][33];
    const int y = blockIdx.x;
    const int img = blockIdx.y;
    const int frame = img >> 1, bb = img & 1;
    const float* src = (frame ? key : cur) + (long)bb * 128 * 1089;
    const float scale = 33.0f / 129.0f;
    float syf = (y + 0.5f) * scale - 0.5f;
    int sy0 = (int)floorf(syf);
    float wy = syf - (float)sy0;
    int sy0c = sy0 < 0 ? 0 : sy0;
    int sy1c = (sy0 + 1 > 32) ? 32 : sy0 + 1;
    for (int e = threadIdx.x; e < 2 * 128 * 33; e += 256) {
        int rr = e / 4224;
        int rem = e - rr * 4224;
        int c = rem / 33, sx = rem - c * 33;
        rows[rr][c][sx] = src[((long)c * 33 + (rr ? sy1c : sy0c)) * 33 + sx];
    }
    __syncthreads();
    u16* dst = U + ((long)(img * HP + (y + 1)) * HP + 1) * 128;
    for (int e = threadIdx.x; e < 129 * 128; e += 256) {
        int x = e >> 7, c = e & 127;
        float sxf = (x + 0.5f) * scale - 0.5f;
        int sx0 = (int)floorf(sxf);
        float wx = sxf - (float)sx0;
        int sx0c = sx0 < 0 ? 0 : sx0;
        int sx1c = (sx0 + 1 > 32) ? 32 : sx0 + 1;
        float v0 = rows[0][c][sx0c] * (1.f - wx) + rows[0][c][sx1c] * wx;
        float v1 = rows[1][c][sx0c] * (1.f - wx) + rows[1][c][sx1c] * wx;
        dst[(long)x * 128 + c] = f2bf(v0 * (1.f - wy) + v1 * wy);
    }
}

// implicit-GEMM 3x3 conv via MFMA, 128x128 tile, BK=32 — r4 swizzle inner
// loop (verified conflicts = 0). SPLIT=2: split-K into separate bf16 partial
// buffers (bias in half 0, no relu); conv3 combines.
//
// VERIFIED round-3 version (126 µs conv2, 622 TF). Tile/schedule space is
// exhausted: r1 counted-vmcnt = null; r6 256x128(co-major) = -26% (FETCH 2x,
// occ 12.7%); r8 128x256(px-major) = -92% (VGPR 156 -> occ 8.3%). 128x128 /
// 64x64-wave matches the 2-barrier structure (guide m105/m112). DO NOT grow
// the wave tile again.
template<int CIN, int MODE, int NWORK, int SPLIT>
__global__ __launch_bounds__(256) void conv_mfma(
        const u16* __restrict__ In, const u16* __restrict__ Wt,
        const float* __restrict__ bias,
        u16* __restrict__ Out0, u16* __restrict__ Out1) {
    constexpr int KC  = CIN / 32;
    constexpr int NS  = 9 * KC;
    constexpr int NSH = NS / SPLIT;
    constexpr int PER = (NWORK + 7) / 8;
    __shared__ u16 As[3][128 * 32];
    __shared__ u16 Bs[3][128 * 32];

    const int id = blockIdx.x;
    const int work = (id & 7) * PER + (id >> 3);
    if (work >= NWORK) return;
    int w = work;
    const int m0 = (w & 1) * 128; w >>= 1;
    int half = 0;
    if (SPLIT == 2) { half = w & 1; w >>= 1; }
    const int xi  = w % 131;
    const int img = w / 131;
    const int p0  = xi * 128;

    const int t    = threadIdx.x;
    const int srow = t >> 2;
    const int scol = ((((t & 3) - (srow >> 1)) & 3) * 8);
    long ub[2];
    #pragma unroll
    for (int is = 0; is < 2; ++is) {
        int p = p0 + srow + is * 64; if (p > NPIX - 1) p = NPIX - 1;
        int y = p / 129, x = p - y * 129;
        ub[is] = ((long)(img * HP + y) * HP + x) * CIN + scol;
    }
    const long wb0 = (long)(m0 + srow) * CIN + scol;

    const int lane = t & 63;
    const int wave = t >> 6;
    const int wm = wave & 1, wn = wave >> 1;
    const int lm = lane & 15, lq = lane >> 4;
    const int koff = (((lq + (lm >> 1)) & 3) * 8);

    auto stage = [&](int s, int buf) {
        const int tap = s / KC;
        const int kc  = (s - tap * KC) * 32;
        const int ky = tap / 3, kx = tap - ky * 3;
        const long toff = (long)(ky * HP + kx) * CIN + kc;
        const u16* WtT = Wt + (long)tap * 256 * CIN + kc;
        char* Aw = (char*)&As[buf][0] + wave * 1024;
        char* Bw = (char*)&Bs[buf][0] + wave * 1024;
        async_cp16(WtT + wb0,             Aw);
        async_cp16(WtT + wb0 + 64L * CIN, Aw + 4096);
        async_cp16(In + ub[0] + toff,     Bw);
        async_cp16(In + ub[1] + toff,     Bw + 4096);
    };

    f32x4 acc[4][4];
    f32x4 zero = {0.f, 0.f, 0.f, 0.f};
    #pragma unroll
    for (int mt = 0; mt < 4; ++mt)
        #pragma unroll
        for (int nt = 0; nt < 4; ++nt) acc[mt][nt] = zero;

    const int s0 = half * NSH;
    stage(s0 + 0, 0);
    stage(s0 + 1, 1);
    #pragma unroll 2
    for (int i = 0; i < NSH; ++i) {
        const int buf = i % 3;
        // counted wait: with <=8 outstanding, vmcnt(4) completes the oldest
        // stage-group = stage(i). Last iter has only stage(NSH-1) in flight.
        if (i < NSH - 1) asm volatile("s_waitcnt vmcnt(4)" ::: "memory");
        else             asm volatile("s_waitcnt vmcnt(0)" ::: "memory");
        __builtin_amdgcn_s_barrier();
        asm volatile("" ::: "memory");
        if (i + 2 < NSH) stage(s0 + i + 2, (i + 2) % 3);
        s16x8 fa[4], fb[4];
        #pragma unroll
        for (int mt = 0; mt < 4; ++mt)
            fa[mt] = *(const s16x8*)&As[buf][(wm * 64 + mt * 16 + lm) * 32 + koff];
        #pragma unroll
        for (int nt = 0; nt < 4; ++nt)
            fb[nt] = *(const s16x8*)&Bs[buf][(wn * 64 + nt * 16 + lm) * 32 + koff];
        #pragma unroll
        for (int mt = 0; mt < 4; ++mt)
            #pragma unroll
            for (int nt = 0; nt < 4; ++nt)
                acc[mt][nt] = __builtin_amdgcn_mfma_f32_16x16x32_bf16(
                    fa[mt], fb[nt], acc[mt][nt], 0, 0, 0);
    }

    u16* OutBf = half ? Out1 : Out0;
    #pragma unroll
    for (int nt = 0; nt < 4; ++nt) {
        int p = p0 + wn * 64 + nt * 16 + lm;
        if (p > NPIX - 1) continue;
        long obase;
        if (MODE == 0) {
            int y = p / 129, x = p - y * 129;
            int bb = img & 1, frame = img >> 1;
            obase = ((long)(bb * HP + (y + 1)) * HP + (x + 1)) * 512 + frame * 256;
        } else {
            obase = ((long)img * NPIX + p) * 256;
        }
        #pragma unroll
        for (int mt = 0; mt < 4; ++mt) {
            int co = m0 + wm * 64 + mt * 16 + lq * 4;
            f32x4 bv = *(const f32x4*)(bias + co);
            if (MODE == 0) {
                float v0 = fmaxf(acc[mt][nt][0] + bv[0], 0.f);
                float v1 = fmaxf(acc[mt][nt][1] + bv[1], 0.f);
                float v2 = fmaxf(acc[mt][nt][2] + bv[2], 0.f);
                float v3 = fmaxf(acc[mt][nt][3] + bv[3], 0.f);
                u16x4 o = { f2bf(v0), f2bf(v1), f2bf(v2), f2bf(v3) };
                *(u16x4*)(OutBf + obase + co) = o;
            } else {
                float bs = half ? 0.f : 1.f;
                u16x4 o = { f2bf(acc[mt][nt][0] + bs * bv[0]),
                            f2bf(acc[mt][nt][1] + bs * bv[1]),
                            f2bf(acc[mt][nt][2] + bs * bv[2]),
                            f2bf(acc[mt][nt][3] + bs * bv[3]) };
                *(u16x4*)(OutBf + obase + co) = o;
            }
        }
    }
}

// combine split-K halves (add, relu) + 1x1 conv (256->49) + softmax.
// 4 threads/pixel (64 ch each), LDS reduce. P written [img][pix][52].
__global__ __launch_bounds__(256) void conv3_softmax(
        const u16* __restrict__ Xa, const u16* __restrict__ Xb,
        const float* __restrict__ W3t, const float* __restrict__ b3,
        float* __restrict__ P) {
    __shared__ float red[3][64][50];
    const int t = threadIdx.x;
    const int pl = t & 63, sub = t >> 6;
    const int idx = blockIdx.x * 64 + pl;
    const bool valid = idx < 2 * NPIX;
    float l[49];
    #pragma unroll
    for (int k = 0; k < 49; ++k) l[k] = 0.f;
    if (valid) {
        const s16x8* xra = (const s16x8*)(Xa + (long)idx * 256 + sub * 64);
        const s16x8* xrb = (const s16x8*)(Xb + (long)idx * 256 + sub * 64);
        #pragma unroll 1
        for (int cb = 0; cb < 8; ++cb) {
            s16x8 av = xra[cb];
            s16x8 bv = xrb[cb];
            #pragma unroll
            for (int j = 0; j < 8; ++j) {
                float xc = fmaxf(bf2f((u16)av[j]) + bf2f((u16)bv[j]), 0.f);
                const float* wrow = W3t + (sub * 64 + cb * 8 + j) * 49;
                #pragma unroll
                for (int k = 0; k < 49; ++k) l[k] = fmaf(wrow[k], xc, l[k]);
            }
        }
    }
    if (sub) {
        #pragma unroll
        for (int k = 0; k < 49; ++k) red[sub - 1][pl][k] = l[k];
    }
    __syncthreads();
    if (!sub && valid) {
        float m = 0.f;
        #pragma unroll
        for (int k = 0; k < 49; ++k) {
            l[k] = fmaxf(l[k] + red[0][pl][k] + red[1][pl][k] + red[2][pl][k]
                         + b3[k], 0.f);
            m = fmaxf(m, l[k]);
        }
        float ssum = 0.f;
        #pragma unroll
        for (int k = 0; k < 49; ++k) { l[k] = __expf(l[k] - m); ssum += l[k]; }
        float inv = 1.f / ssum;
        int bb = idx / NPIX, pix = idx - bb * NPIX;
        float* Pp = P + ((long)bb * NPIX + pix) * 52;
        #pragma unroll
        for (int k = 0; k < 49; ++k) Pp[k] = l[k] * inv;
    }
}

// transpose-pad: F NCHW [2][256][129][129] -> Fp NHWC [2][135][135][256]
// with 3-px zero halo. Block = (yyp, img, 64-ch group); LDS tile [64][133]
// (pad 133: stride 5 banks, conflict-free transpose reads). Reads coalesced
// along x; writes coalesced along ch (256B per xx).
__global__ __launch_bounds__(256) void tpad(
        const float* __restrict__ F, float* __restrict__ Fp) {
    __shared__ float T[64][133];
    const int yyp = blockIdx.x;        // 0..134
    const int img = blockIdx.y;        // 0..1
    const int cb  = blockIdx.z;        // 0..3
    const int t = threadIdx.x;
    const int yo = yyp - 3;
    float* dst = Fp + (((long)img * FPY + yyp) * FPY) * 256 + cb * 64;
    if ((unsigned)yo > 128u) {
        for (int e = t; e < FPY * 64; e += 256) {
            int xx = e >> 6, c = e & 63;
            dst[(long)xx * 256 + c] = 0.f;
        }
        return;
    }
    const float* src = F + ((long)(img * 256 + cb * 64)) * NPIX + yo * 129;
    for (int e = t; e < 64 * 129; e += 256) {
        int c = e / 129, x = e - c * 129;
        T[c][x] = src[(long)c * NPIX + x];
    }
    __syncthreads();
    for (int e = t; e < FPY * 64; e += 256) {
        int xx = e >> 6, c = e & 63;
        int xo = xx - 3;
        dst[(long)xx * 256 + c] = ((unsigned)xo <= 128u) ? T[c][xo] : 0.f;
    }
}

// spatially-variant 7x7 conv v7: lanes = channels (NHWC F). One wave owns a
// 2x2 pixel quad x all 256 ch (lane l -> ch 4l..4l+3). Every F tap is ONE
// aligned coalesced dwordx4/lane (1KB/wave); w is wave-uniform, streamed
// per kernel-row (<=32 regs live); 8 rows x 8 cols of F feed all 4 pixels
// (4x reuse). Block = 8 waves = 16 consecutive x; output transposed through
// LDS [2][16][260] so NCHW stores are full 64B lines. Tap order (ky asc,
// kx asc) identical to v4; skipped-tap w regs are zero-init (exact +0 terms)
// -> numerics identical. Invalid-pixel accs land in LDS slots never read.
__global__ __launch_bounds__(512) void svconv(
        const float* __restrict__ Fp, const float* __restrict__ P,
        float* __restrict__ Out) {
    __shared__ float Ls[2][16][260];
    const int id  = blockIdx.x;            // 1170 = 2 img x 65 yp x 9 xg
    const int img = id / 585;
    const int rr  = id - img * 585;
    const int yp  = rr / 9, xg = rr - yp * 9;
    const int y   = 2 * yp;                // 0..128
    const int tid = threadIdx.x;
    const int lane = tid & 63, wv = tid >> 6;
    const int x = xg * 16 + 2 * wv;        // 0..142
    const bool has_y1 = (y < 128);
    const bool active = (x <= 128);
    const bool has_x1 = (x < 128);

    if (active) {
        const int px0 = y * 129 + x;
        const float* Pw00 = P + ((long)img * NPIX + px0) * 52;
        const float* Pw01 = Pw00 + 52;
        const float* Pw10 = Pw00 + 129 * 52;
        const float* Pw11 = Pw10 + 52;
        const float* Fb = Fp + (((long)img * FPY + y) * FPY + x) * 256 + 4 * lane;

        f32x4 z4 = {0.f, 0.f, 0.f, 0.f};
        f32x4 acc00 = z4, acc01 = z4, acc10 = z4, acc11 = z4;
        #pragma unroll
        for (int r = 0; r < 8; ++r) {
            if (r == 7 && !has_y1) break;   // row y+7 would be OOB; y1-only
            f32x4 a00 = z4, b00 = z4, a01 = z4, b01 = z4;
            f32x4 a10 = z4, b10 = z4, a11 = z4, b11 = z4;
            if (r < 7) {
                a00 = *(const f32x4u*)(Pw00 + r * 7);
                b00 = *(const f32x4u*)(Pw00 + r * 7 + 3);
                if (has_x1) {
                    a01 = *(const f32x4u*)(Pw01 + r * 7);
                    b01 = *(const f32x4u*)(Pw01 + r * 7 + 3);
                }
            }
            if (r >= 1 && has_y1) {
                a10 = *(const f32x4u*)(Pw10 + (r - 1) * 7);
                b10 = *(const f32x4u*)(Pw10 + (r - 1) * 7 + 3);
                if (has_x1) {
                    a11 = *(const f32x4u*)(Pw11 + (r - 1) * 7);
                    b11 = *(const f32x4u*)(Pw11 + (r - 1) * 7 + 3);
                }
            }
            const float* Fr = Fb + (long)r * FPY * 256;
            f32x4 f[8];
            #pragma unroll
            for (int q = 0; q < 7; ++q) f[q] = *(const f32x4*)(Fr + q * 256);
            if (has_x1) f[7] = *(const f32x4*)(Fr + 7 * 256);
            else        f[7] = z4;
            #pragma unroll
            for (int q = 0; q < 8; ++q) {
                if (q < 7) {
                    float w0 = (q < 4) ? a00[q] : b00[q - 3];
                    acc00 += w0 * f[q];
                    float w2 = (q < 4) ? a10[q] : b10[q - 3];
                    acc10 += w2 * f[q];
                }
                if (q >= 1) {
                    const int k = q - 1;
                    float w1 = (k < 4) ? a01[k] : b01[k - 3];
                    acc01 += w1 * f[q];
                    float w3 = (k < 4) ? a11[k] : b11[k - 3];
                    acc11 += w3 * f[q];
                }
            }
        }
        const int xr = 2 * wv;
        *(f32x4*)&Ls[0][xr    ][4 * lane] = acc00;
        *(f32x4*)&Ls[0][xr + 1][4 * lane] = acc01;
        *(f32x4*)&Ls[1][xr    ][4 * lane] = acc10;
        *(f32x4*)&Ls[1][xr + 1][4 * lane] = acc11;
    }
    __syncthreads();

    const int ch = tid & 255, dy = tid >> 8;
    if (dy && !has_y1) return;
    float* Ob = Out + ((long)(img * 256 + ch)) * NPIX + (y + dy) * 129 + xg * 16;
    if (xg < 8) {
        float o[16];
        #pragma unroll
        for (int xx = 0; xx < 16; ++xx) o[xx] = Ls[dy][xx][ch];
        #pragma unroll
        for (int k2 = 0; k2 < 4; ++k2)
            *(f32x4u*)(Ob + 4 * k2) = *(f32x4*)&o[4 * k2];
    } else {
        Ob[0] = Ls[dy][0][ch];   // xg==8: only x=128 valid
    }
}

extern "C" void kernel_launch(void* const* d_in, const int* in_sizes, int n_in,
                              void* d_out, int out_size, void* d_ws, size_t ws_size,
                              hipStream_t stream) {
    const float* cur      = (const float*)d_in[0];
    const float* key      = (const float*)d_in[1];
    const float* Fhigh    = (const float*)d_in[2];
    const float* w_reduce = (const float*)d_in[3];
    const float* b_reduce = (const float*)d_in[4];
    const float* w_conv2  = (const float*)d_in[5];
    const float* b_conv2  = (const float*)d_in[6];
    const float* w_conv3  = (const float*)d_in[7];
    const float* b_conv3  = (const float*)d_in[8];

    if (ws_size < 89798656UL) return;

    char* ws = (char*)d_ws;
    // phase 1 (through conv2)
    u16*   U     = (u16*)(ws + 0);
    u16*   S1    = (u16*)(ws + 17572864);
    // phase 2 (after conv2; overlays U/S1 region)
    float* Fp    = (float*)(ws + 0);           // 37,324,800 B NHWC padded
    float* P     = (float*)(ws + 37601280);    //  6,922,656 B
    u16*   Wt1   = (u16*)(ws + 52718592);
    u16*   Wt2   = (u16*)(ws + 53308416);
    u16*   out2a = (u16*)(ws + 55667712);
    u16*   out2b = (u16*)(ws + 72708096);
    float* w3t   = (float*)(ws + 89748480);

    zero_border<<<dim3(130, 6), 256, 0, stream>>>(U, S1);
    prep_weights<<<5809, 256, 0, stream>>>(w_reduce, w_conv2, w_conv3, Wt1, Wt2, w3t);
    upsample<<<dim3(129, 4), 256, 0, stream>>>(cur, key, U);
    conv_mfma<128, 0, 1048, 1><<<1048, 256, 0, stream>>>(U, Wt1, b_reduce, S1, S1);
    conv_mfma<512, 1, 1048, 2><<<1048, 256, 0, stream>>>(S1, Wt2, b_conv2, out2a, out2b);
    tpad<<<dim3(FPY, 2, 4), 256, 0, stream>>>(Fhigh, Fp);  // overlays U/S1 (dead)
    conv3_softmax<<<521, 256, 0, stream>>>(out2a, out2b, w3t, b_conv3, P);
    svconv<<<1170, 512, 0, stream>>>(Fp, P, (float*)d_out);
}

// Round 8
// 468.397 us; speedup vs baseline: 1.7118x; 1.7118x over previous
//
#include <hip/hip_runtime.h>

typedef unsigned short u16;
typedef unsigned int   u32;
typedef __attribute__((ext_vector_type(8))) short s16x8;
typedef __attribute__((ext_vector_type(4))) float f32x4;
typedef __attribute__((ext_vector_type(4), aligned(4))) float f32x4u;  // 4B-aligned vec load
typedef __attribute__((ext_vector_type(4))) u32   u32x4;
typedef __attribute__((ext_vector_type(4))) u16   u16x4;

#define NPIX 16641   /* 129*129 */
#define HP   131     /* padded spatial dim (convs) */
#define FPY  135     /* NHWC padded spatial dim (svconv: 129 + 3+3) */

// ---- workspace layout (bytes) ----
// region A (two lifetimes):
//   phase 1: U [4][131][131][128] bf16 @ 0 (17.6M), S1 [2][131][131][512] bf16 @ 17572864 (35.1M)
//   phase 2 (after conv2): Fp [2][135][135][256] f32 NHWC @ 0 (37,324,800)
//                          P  [2][16641][52] f32        @ 37601280 (6,922,656)
// Wt1  : [9][256][128] bf16  @ 52718592   (589,824)
// Wt2  : [9][256][512] bf16  @ 53308416   (2,359,296)
// out2a: [2*16641][256] bf16 @ 55667712   (17,040,384)  split-K half 0 (pre-relu, +bias)
// out2b: [2*16641][256] bf16 @ 72708096   (17,040,384)  split-K half 1
// w3t  : [256][49] f32       @ 89748480   (50,176)
// total required: 89,798,656 B

__device__ __forceinline__ u16 f2bf(float f) {
    u32 b = __builtin_bit_cast(u32, f);
    return (u16)((b + 0x7fffu + ((b >> 16) & 1u)) >> 16);
}
__device__ __forceinline__ float bf2f(u16 u) {
    return __builtin_bit_cast(float, ((u32)u) << 16);
}

// async global->LDS, 16B per lane; LDS dest wave-uniform base, lane l -> +16*l
__device__ __forceinline__ void async_cp16(const void* g, void* l) {
    __builtin_amdgcn_global_load_lds(
        (const __attribute__((address_space(1))) u32*)g,
        (__attribute__((address_space(3))) u32*)l, 16, 0, 0);
}

// zero only the 1-pixel pad ring of U (4 imgs, C=128) and S1 (2 imgs, C=512).
__global__ __launch_bounds__(256) void zero_border(u16* __restrict__ U,
                                                   u16* __restrict__ S1) {
    const int plane = blockIdx.y;           // 0..3: U, 4..5: S1
    const bool isU = plane < 4;
    const int C = isU ? 128 : 512;
    const int cpp = C / 8;
    int e = blockIdx.x * 256 + threadIdx.x;
    if (e >= 520 * cpp) return;
    int pix = e / cpp, ch = e - pix * cpp;
    int r, c;
    if (pix < 131)      { r = 0;   c = pix; }
    else if (pix < 262) { r = 130; c = pix - 131; }
    else { int j = pix - 262; r = 1 + (j >> 1); c = (j & 1) ? 130 : 0; }
    int img = isU ? plane : (plane - 4);
    u16* base = (isU ? U : S1) + ((long)(img * HP + r) * HP + c) * C + ch * 8;
    u32x4 z = {0u, 0u, 0u, 0u};
    *(u32x4*)base = z;
}

// transform weights: Wt[tap][co][ci] (bf16), w3t[c][t] (f32)
__global__ __launch_bounds__(256) void prep_weights(
        const float* __restrict__ wr, const float* __restrict__ w2,
        const float* __restrict__ w3,
        u16* __restrict__ Wt1, u16* __restrict__ Wt2, float* __restrict__ w3t) {
    int i = blockIdx.x * 256 + threadIdx.x;
    if (i < 294912) {
        int tap = i / 32768, r = i & 32767;
        int co = r >> 7, ci = r & 127;
        Wt1[i] = f2bf(wr[(co * 128 + ci) * 9 + tap]);
    } else if (i < 1474560) {
        int j = i - 294912;
        int tap = j / 131072, r = j & 131071;
        int co = r >> 9, ci = r & 511;
        Wt2[j] = f2bf(w2[(co * 512 + ci) * 9 + tap]);
    } else if (i < 1487104) {
        int j = i - 1474560;
        int c = j / 49, t = j - c * 49;
        w3t[j] = w3[t * 256 + c];
    }
}

// bilinear upsample 33x33 -> 129x129, write padded NHWC bf16
__global__ __launch_bounds__(256) void upsample(
        const float* __restrict__ cur, const float* __restrict__ key,
        u16* __restrict__ U) {
    __shared__ float rows[2][128][33];
    const int y = blockIdx.x;
    const int img = blockIdx.y;
    const int frame = img >> 1, bb = img & 1;
    const float* src = (frame ? key : cur) + (long)bb * 128 * 1089;
    const float scale = 33.0f / 129.0f;
    float syf = (y + 0.5f) * scale - 0.5f;
    int sy0 = (int)floorf(syf);
    float wy = syf - (float)sy0;
    int sy0c = sy0 < 0 ? 0 : sy0;
    int sy1c = (sy0 + 1 > 32) ? 32 : sy0 + 1;
    for (int e = threadIdx.x; e < 2 * 128 * 33; e += 256) {
        int rr = e / 4224;
        int rem = e - rr * 4224;
        int c = rem / 33, sx = rem - c * 33;
        rows[rr][c][sx] = src[((long)c * 33 + (rr ? sy1c : sy0c)) * 33 + sx];
    }
    __syncthreads();
    u16* dst = U + ((long)(img * HP + (y + 1)) * HP + 1) * 128;
    for (int e = threadIdx.x; e < 129 * 128; e += 256) {
        int x = e >> 7, c = e & 127;
        float sxf = (x + 0.5f) * scale - 0.5f;
        int sx0 = (int)floorf(sxf);
        float wx = sxf - (float)sx0;
        int sx0c = sx0 < 0 ? 0 : sx0;
        int sx1c = (sx0 + 1 > 32) ? 32 : sx0 + 1;
        float v0 = rows[0][c][sx0c] * (1.f - wx) + rows[0][c][sx1c] * wx;
        float v1 = rows[1][c][sx0c] * (1.f - wx) + rows[1][c][sx1c] * wx;
        dst[(long)x * 128 + c] = f2bf(v0 * (1.f - wy) + v1 * wy);
    }
}

// implicit-GEMM 3x3 conv via MFMA, 128x128 tile, BK=32 — r4 swizzle inner
// loop (verified conflicts = 0). SPLIT=2: split-K into separate bf16 partial
// buffers (bias in half 0, no relu); conv3 combines.
//
// VERIFIED round-3 version (126 µs conv2, 622 TF). Tile/schedule space is
// exhausted: r1 counted-vmcnt = null; r6 256x128(co-major) = -26% (FETCH 2x,
// occ 12.7%); r8 128x256(px-major) = -92% (VGPR 156 -> occ 8.3%). 128x128 /
// 64x64-wave matches the 2-barrier structure (guide m105/m112). DO NOT grow
// the wave tile again.
template<int CIN, int MODE, int NWORK, int SPLIT>
__global__ __launch_bounds__(256) void conv_mfma(
        const u16* __restrict__ In, const u16* __restrict__ Wt,
        const float* __restrict__ bias,
        u16* __restrict__ Out0, u16* __restrict__ Out1) {
    constexpr int KC  = CIN / 32;
    constexpr int NS  = 9 * KC;
    constexpr int NSH = NS / SPLIT;
    constexpr int PER = (NWORK + 7) / 8;
    __shared__ u16 As[3][128 * 32];
    __shared__ u16 Bs[3][128 * 32];

    const int id = blockIdx.x;
    const int work = (id & 7) * PER + (id >> 3);
    if (work >= NWORK) return;
    int w = work;
    const int m0 = (w & 1) * 128; w >>= 1;
    int half = 0;
    if (SPLIT == 2) { half = w & 1; w >>= 1; }
    const int xi  = w % 131;
    const int img = w / 131;
    const int p0  = xi * 128;

    const int t    = threadIdx.x;
    const int srow = t >> 2;
    const int scol = ((((t & 3) - (srow >> 1)) & 3) * 8);
    long ub[2];
    #pragma unroll
    for (int is = 0; is < 2; ++is) {
        int p = p0 + srow + is * 64; if (p > NPIX - 1) p = NPIX - 1;
        int y = p / 129, x = p - y * 129;
        ub[is] = ((long)(img * HP + y) * HP + x) * CIN + scol;
    }
    const long wb0 = (long)(m0 + srow) * CIN + scol;

    const int lane = t & 63;
    const int wave = t >> 6;
    const int wm = wave & 1, wn = wave >> 1;
    const int lm = lane & 15, lq = lane >> 4;
    const int koff = (((lq + (lm >> 1)) & 3) * 8);

    auto stage = [&](int s, int buf) {
        const int tap = s / KC;
        const int kc  = (s - tap * KC) * 32;
        const int ky = tap / 3, kx = tap - ky * 3;
        const long toff = (long)(ky * HP + kx) * CIN + kc;
        const u16* WtT = Wt + (long)tap * 256 * CIN + kc;
        char* Aw = (char*)&As[buf][0] + wave * 1024;
        char* Bw = (char*)&Bs[buf][0] + wave * 1024;
        async_cp16(WtT + wb0,             Aw);
        async_cp16(WtT + wb0 + 64L * CIN, Aw + 4096);
        async_cp16(In + ub[0] + toff,     Bw);
        async_cp16(In + ub[1] + toff,     Bw + 4096);
    };

    f32x4 acc[4][4];
    f32x4 zero = {0.f, 0.f, 0.f, 0.f};
    #pragma unroll
    for (int mt = 0; mt < 4; ++mt)
        #pragma unroll
        for (int nt = 0; nt < 4; ++nt) acc[mt][nt] = zero;

    const int s0 = half * NSH;
    stage(s0 + 0, 0);
    stage(s0 + 1, 1);
    #pragma unroll 2
    for (int i = 0; i < NSH; ++i) {
        const int buf = i % 3;
        // counted wait: with <=8 outstanding, vmcnt(4) completes the oldest
        // stage-group = stage(i). Last iter has only stage(NSH-1) in flight.
        if (i < NSH - 1) asm volatile("s_waitcnt vmcnt(4)" ::: "memory");
        else             asm volatile("s_waitcnt vmcnt(0)" ::: "memory");
        __builtin_amdgcn_s_barrier();
        asm volatile("" ::: "memory");
        if (i + 2 < NSH) stage(s0 + i + 2, (i + 2) % 3);
        s16x8 fa[4], fb[4];
        #pragma unroll
        for (int mt = 0; mt < 4; ++mt)
            fa[mt] = *(const s16x8*)&As[buf][(wm * 64 + mt * 16 + lm) * 32 + koff];
        #pragma unroll
        for (int nt = 0; nt < 4; ++nt)
            fb[nt] = *(const s16x8*)&Bs[buf][(wn * 64 + nt * 16 + lm) * 32 + koff];
        #pragma unroll
        for (int mt = 0; mt < 4; ++mt)
            #pragma unroll
            for (int nt = 0; nt < 4; ++nt)
                acc[mt][nt] = __builtin_amdgcn_mfma_f32_16x16x32_bf16(
                    fa[mt], fb[nt], acc[mt][nt], 0, 0, 0);
    }

    u16* OutBf = half ? Out1 : Out0;
    #pragma unroll
    for (int nt = 0; nt < 4; ++nt) {
        int p = p0 + wn * 64 + nt * 16 + lm;
        if (p > NPIX - 1) continue;
        long obase;
        if (MODE == 0) {
            int y = p / 129, x = p - y * 129;
            int bb = img & 1, frame = img >> 1;
            obase = ((long)(bb * HP + (y + 1)) * HP + (x + 1)) * 512 + frame * 256;
        } else {
            obase = ((long)img * NPIX + p) * 256;
        }
        #pragma unroll
        for (int mt = 0; mt < 4; ++mt) {
            int co = m0 + wm * 64 + mt * 16 + lq * 4;
            f32x4 bv = *(const f32x4*)(bias + co);
            if (MODE == 0) {
                float v0 = fmaxf(acc[mt][nt][0] + bv[0], 0.f);
                float v1 = fmaxf(acc[mt][nt][1] + bv[1], 0.f);
                float v2 = fmaxf(acc[mt][nt][2] + bv[2], 0.f);
                float v3 = fmaxf(acc[mt][nt][3] + bv[3], 0.f);
                u16x4 o = { f2bf(v0), f2bf(v1), f2bf(v2), f2bf(v3) };
                *(u16x4*)(OutBf + obase + co) = o;
            } else {
                float bs = half ? 0.f : 1.f;
                u16x4 o = { f2bf(acc[mt][nt][0] + bs * bv[0]),
                            f2bf(acc[mt][nt][1] + bs * bv[1]),
                            f2bf(acc[mt][nt][2] + bs * bv[2]),
                            f2bf(acc[mt][nt][3] + bs * bv[3]) };
                *(u16x4*)(OutBf + obase + co) = o;
            }
        }
    }
}

// combine split-K halves (add, relu) + 1x1 conv (256->49) + softmax.
// 4 threads/pixel (64 ch each), LDS reduce. P written [img][pix][52].
__global__ __launch_bounds__(256) void conv3_softmax(
        const u16* __restrict__ Xa, const u16* __restrict__ Xb,
        const float* __restrict__ W3t, const float* __restrict__ b3,
        float* __restrict__ P) {
    __shared__ float red[3][64][50];
    const int t = threadIdx.x;
    const int pl = t & 63, sub = t >> 6;
    const int idx = blockIdx.x * 64 + pl;
    const bool valid = idx < 2 * NPIX;
    float l[49];
    #pragma unroll
    for (int k = 0; k < 49; ++k) l[k] = 0.f;
    if (valid) {
        const s16x8* xra = (const s16x8*)(Xa + (long)idx * 256 + sub * 64);
        const s16x8* xrb = (const s16x8*)(Xb + (long)idx * 256 + sub * 64);
        #pragma unroll 1
        for (int cb = 0; cb < 8; ++cb) {
            s16x8 av = xra[cb];
            s16x8 bv = xrb[cb];
            #pragma unroll
            for (int j = 0; j < 8; ++j) {
                float xc = fmaxf(bf2f((u16)av[j]) + bf2f((u16)bv[j]), 0.f);
                const float* wrow = W3t + (sub * 64 + cb * 8 + j) * 49;
                #pragma unroll
                for (int k = 0; k < 49; ++k) l[k] = fmaf(wrow[k], xc, l[k]);
            }
        }
    }
    if (sub) {
        #pragma unroll
        for (int k = 0; k < 49; ++k) red[sub - 1][pl][k] = l[k];
    }
    __syncthreads();
    if (!sub && valid) {
        float m = 0.f;
        #pragma unroll
        for (int k = 0; k < 49; ++k) {
            l[k] = fmaxf(l[k] + red[0][pl][k] + red[1][pl][k] + red[2][pl][k]
                         + b3[k], 0.f);
            m = fmaxf(m, l[k]);
        }
        float ssum = 0.f;
        #pragma unroll
        for (int k = 0; k < 49; ++k) { l[k] = __expf(l[k] - m); ssum += l[k]; }
        float inv = 1.f / ssum;
        int bb = idx / NPIX, pix = idx - bb * NPIX;
        float* Pp = P + ((long)bb * NPIX + pix) * 52;
        #pragma unroll
        for (int k = 0; k < 49; ++k) Pp[k] = l[k] * inv;
    }
}

// transpose-pad: F NCHW [2][256][129][129] -> Fp NHWC [2][135][135][256]
// with 3-px zero halo. Block = (yyp, img, 64-ch group); LDS tile [64][133]
// (pad 133: stride 5 banks, conflict-free transpose reads). Reads coalesced
// along x; writes coalesced along ch (256B per xx).
__global__ __launch_bounds__(256) void tpad(
        const float* __restrict__ F, float* __restrict__ Fp) {
    __shared__ float T[64][133];
    const int yyp = blockIdx.x;        // 0..134
    const int img = blockIdx.y;        // 0..1
    const int cb  = blockIdx.z;        // 0..3
    const int t = threadIdx.x;
    const int yo = yyp - 3;
    float* dst = Fp + (((long)img * FPY + yyp) * FPY) * 256 + cb * 64;
    if ((unsigned)yo > 128u) {
        for (int e = t; e < FPY * 64; e += 256) {
            int xx = e >> 6, c = e & 63;
            dst[(long)xx * 256 + c] = 0.f;
        }
        return;
    }
    const float* src = F + ((long)(img * 256 + cb * 64)) * NPIX + yo * 129;
    for (int e = t; e < 64 * 129; e += 256) {
        int c = e / 129, x = e - c * 129;
        T[c][x] = src[(long)c * NPIX + x];
    }
    __syncthreads();
    for (int e = t; e < FPY * 64; e += 256) {
        int xx = e >> 6, c = e & 63;
        int xo = xx - 3;
        dst[(long)xx * 256 + c] = ((unsigned)xo <= 128u) ? T[c][xo] : 0.f;
    }
}

// spatially-variant 7x7 conv v8 = v7 architecture with the spill fixed.
// r7 failure: 512-thread block capped VGPR at 128; inner loop held 8 weight
// vectors + f[8] -> scratch spill (WRITE_SIZE 781 MB vs 34 MB output).
// v8: 256-thread block (4 waves, VGPR cap 256) and SEQUENTIAL per-pixel
// weight application (load 2 weight vecs, apply 7 FMAs, release) -> peak
// live ~80 regs. Wave = 2x2 pixel quad x 256 ch (lane l -> ch 4l..4l+3):
// every F tap is one aligned coalesced dwordx4/lane, 4x F reuse, w wave-
// uniform. Block = 4 waves = 8 x; output transposed through LDS [2][8][260]
// so NCHW stores are contiguous 32B/thread. Per-acc term order (r asc, tap
// asc) identical to v7/v4 -> numerics identical.
__global__ __launch_bounds__(256) void svconv(
        const float* __restrict__ Fp, const float* __restrict__ P,
        float* __restrict__ Out) {
    __shared__ float Ls[2][8][260];
    const int id  = blockIdx.x;            // 2210 = 2 img x 65 yp x 17 xg
    const int img = id / 1105;
    const int rr  = id - img * 1105;
    const int yp  = rr / 17, xg = rr - yp * 17;
    const int y   = 2 * yp;                // 0..128
    const int tid = threadIdx.x;
    const int lane = tid & 63, wv = tid >> 6;
    const int x = xg * 8 + 2 * wv;         // 0..134
    const bool has_y1 = (y < 128);
    const bool active = (x <= 128);
    const bool has_x1 = (x < 128);

    if (active) {
        const int px0 = y * 129 + x;
        const float* Pw00 = P + ((long)img * NPIX + px0) * 52;
        const float* Pw01 = Pw00 + 52;
        const float* Pw10 = Pw00 + 129 * 52;
        const float* Pw11 = Pw10 + 52;
        const float* Fb = Fp + (((long)img * FPY + y) * FPY + x) * 256 + 4 * lane;

        f32x4 z4 = {0.f, 0.f, 0.f, 0.f};
        f32x4 acc00 = z4, acc01 = z4, acc10 = z4, acc11 = z4;
        #pragma unroll
        for (int r = 0; r < 8; ++r) {
            if (r == 7 && !has_y1) break;   // row y+7 only feeds the y+1 pair
            const float* Fr = Fb + (long)r * FPY * 256;
            f32x4 f[8];
            #pragma unroll
            for (int q = 0; q < 7; ++q) f[q] = *(const f32x4*)(Fr + q * 256);
            f[7] = has_x1 ? *(const f32x4*)(Fr + 7 * 256) : z4;
            if (r < 7) {
                {
                    f32x4 wa = *(const f32x4u*)(Pw00 + r * 7);
                    f32x4 wb = *(const f32x4u*)(Pw00 + r * 7 + 3);
                    acc00 += wa[0] * f[0]; acc00 += wa[1] * f[1];
                    acc00 += wa[2] * f[2]; acc00 += wa[3] * f[3];
                    acc00 += wb[1] * f[4]; acc00 += wb[2] * f[5];
                    acc00 += wb[3] * f[6];
                }
                if (has_x1) {
                    f32x4 wa = *(const f32x4u*)(Pw01 + r * 7);
                    f32x4 wb = *(const f32x4u*)(Pw01 + r * 7 + 3);
                    acc01 += wa[0] * f[1]; acc01 += wa[1] * f[2];
                    acc01 += wa[2] * f[3]; acc01 += wa[3] * f[4];
                    acc01 += wb[1] * f[5]; acc01 += wb[2] * f[6];
                    acc01 += wb[3] * f[7];
                }
            }
            if (r >= 1 && has_y1) {
                {
                    f32x4 wa = *(const f32x4u*)(Pw10 + (r - 1) * 7);
                    f32x4 wb = *(const f32x4u*)(Pw10 + (r - 1) * 7 + 3);
                    acc10 += wa[0] * f[0]; acc10 += wa[1] * f[1];
                    acc10 += wa[2] * f[2]; acc10 += wa[3] * f[3];
                    acc10 += wb[1] * f[4]; acc10 += wb[2] * f[5];
                    acc10 += wb[3] * f[6];
                }
                if (has_x1) {
                    f32x4 wa = *(const f32x4u*)(Pw11 + (r - 1) * 7);
                    f32x4 wb = *(const f32x4u*)(Pw11 + (r - 1) * 7 + 3);
                    acc11 += wa[0] * f[1]; acc11 += wa[1] * f[2];
                    acc11 += wa[2] * f[3]; acc11 += wa[3] * f[4];
                    acc11 += wb[1] * f[5]; acc11 += wb[2] * f[6];
                    acc11 += wb[3] * f[7];
                }
            }
        }
        const int xr = 2 * wv;
        *(f32x4*)&Ls[0][xr    ][4 * lane] = acc00;
        *(f32x4*)&Ls[0][xr + 1][4 * lane] = acc01;
        *(f32x4*)&Ls[1][xr    ][4 * lane] = acc10;
        *(f32x4*)&Ls[1][xr + 1][4 * lane] = acc11;
    }
    __syncthreads();

    const int ch = tid;                    // 0..255
    #pragma unroll 1
    for (int dy = 0; dy < 2; ++dy) {
        if (dy && !has_y1) break;
        float* Ob = Out + ((long)(img * 256 + ch)) * NPIX + (y + dy) * 129 + xg * 8;
        if (xg < 16) {
            float o[8];
            #pragma unroll
            for (int xx = 0; xx < 8; ++xx) o[xx] = Ls[dy][xx][ch];
            *(f32x4u*)Ob       = *(f32x4*)&o[0];
            *(f32x4u*)(Ob + 4) = *(f32x4*)&o[4];
        } else {
            Ob[0] = Ls[dy][0][ch];         // xg==16: only x=128 valid
        }
    }
}

extern "C" void kernel_launch(void* const* d_in, const int* in_sizes, int n_in,
                              void* d_out, int out_size, void* d_ws, size_t ws_size,
                              hipStream_t stream) {
    const float* cur      = (const float*)d_in[0];
    const float* key      = (const float*)d_in[1];
    const float* Fhigh    = (const float*)d_in[2];
    const float* w_reduce = (const float*)d_in[3];
    const float* b_reduce = (const float*)d_in[4];
    const float* w_conv2  = (const float*)d_in[5];
    const float* b_conv2  = (const float*)d_in[6];
    const float* w_conv3  = (const float*)d_in[7];
    const float* b_conv3  = (const float*)d_in[8];

    if (ws_size < 89798656UL) return;

    char* ws = (char*)d_ws;
    // phase 1 (through conv2)
    u16*   U     = (u16*)(ws + 0);
    u16*   S1    = (u16*)(ws + 17572864);
    // phase 2 (after conv2; overlays U/S1 region)
    float* Fp    = (float*)(ws + 0);           // 37,324,800 B NHWC padded
    float* P     = (float*)(ws + 37601280);    //  6,922,656 B
    u16*   Wt1   = (u16*)(ws + 52718592);
    u16*   Wt2   = (u16*)(ws + 53308416);
    u16*   out2a = (u16*)(ws + 55667712);
    u16*   out2b = (u16*)(ws + 72708096);
    float* w3t   = (float*)(ws + 89748480);

    zero_border<<<dim3(130, 6), 256, 0, stream>>>(U, S1);
    prep_weights<<<5809, 256, 0, stream>>>(w_reduce, w_conv2, w_conv3, Wt1, Wt2, w3t);
    upsample<<<dim3(129, 4), 256, 0, stream>>>(cur, key, U);
    conv_mfma<128, 0, 1048, 1><<<1048, 256, 0, stream>>>(U, Wt1, b_reduce, S1, S1);
    conv_mfma<512, 1, 1048, 2><<<1048, 256, 0, stream>>>(S1, Wt2, b_conv2, out2a, out2b);
    tpad<<<dim3(FPY, 2, 4), 256, 0, stream>>>(Fhigh, Fp);  // overlays U/S1 (dead)
    conv3_softmax<<<521, 256, 0, stream>>>(out2a, out2b, w3t, b_conv3, P);
    svconv<<<2210, 256, 0, stream>>>(Fp, P, (float*)d_out);
}

// Round 9
// 461.352 us; speedup vs baseline: 1.7379x; 1.0153x over previous
//
#include <hip/hip_runtime.h>

typedef unsigned short u16;
typedef unsigned int   u32;
typedef __attribute__((ext_vector_type(8))) short s16x8;
typedef __attribute__((ext_vector_type(4))) float f32x4;
typedef __attribute__((ext_vector_type(4), aligned(4))) float f32x4u;  // 4B-aligned vec load
typedef __attribute__((ext_vector_type(4))) u32   u32x4;
typedef __attribute__((ext_vector_type(4))) u16   u16x4;

#define NPIX 16641   /* 129*129 */
#define HP   131     /* padded spatial dim (convs) */
#define FPH  135     /* svconv padded F: height */
#define FPW  136     /* svconv padded F: row stride */
#define FPC  18360   /* FPH*FPW floats per channel */

// ---- workspace layout (bytes) ----
// region A (two lifetimes):
//   phase 1: U [4][131][131][128] bf16 @ 0 (17.6M), S1 [2][131][131][512] bf16 @ 17572864 (35.1M)
//   phase 2 (after conv2): Fpad [2][256][135][136] f32 @ 0 (37,601,280)
//                          P    [2][16641][52] f32     @ 37601280 (6,922,656)
// Wt1  : [9][256][128] bf16  @ 52718592   (589,824)
// Wt2  : [9][256][512] bf16  @ 53308416   (2,359,296)
// out2a: [2*16641][256] bf16 @ 55667712   (17,040,384)  split-K half 0 (pre-relu, +bias)
// out2b: [2*16641][256] bf16 @ 72708096   (17,040,384)  split-K half 1
// w3t  : [256][49] f32       @ 89748480   (50,176)
// total required: 89,798,656 B
//
// FINAL CONFIG (r3-verified, 461.8 µs): conv_mfma r5-schedule (126 µs/conv),
// fpad + svconv v4 pixel-pair (93 µs), conv3_softmax. Explored and rejected
// with counter evidence: counted-vmcnt deeper pipelines (null), 256x128 and
// 128x256 conv tiles (L2-reuse loss / VGPR-occupancy loss), svconv direct-F
// (scratch spill), LDS-staged svconv (scalar ds_read-bound), NHWC svconv
// (works, but tpad transpose cost nets +7 µs vs fpad+v4).

__device__ __forceinline__ u16 f2bf(float f) {
    u32 b = __builtin_bit_cast(u32, f);
    return (u16)((b + 0x7fffu + ((b >> 16) & 1u)) >> 16);
}
__device__ __forceinline__ float bf2f(u16 u) {
    return __builtin_bit_cast(float, ((u32)u) << 16);
}

// async global->LDS, 16B per lane; LDS dest wave-uniform base, lane l -> +16*l
__device__ __forceinline__ void async_cp16(const void* g, void* l) {
    __builtin_amdgcn_global_load_lds(
        (const __attribute__((address_space(1))) u32*)g,
        (__attribute__((address_space(3))) u32*)l, 16, 0, 0);
}

// zero only the 1-pixel pad ring of U (4 imgs, C=128) and S1 (2 imgs, C=512).
__global__ __launch_bounds__(256) void zero_border(u16* __restrict__ U,
                                                   u16* __restrict__ S1) {
    const int plane = blockIdx.y;           // 0..3: U, 4..5: S1
    const bool isU = plane < 4;
    const int C = isU ? 128 : 512;
    const int cpp = C / 8;
    int e = blockIdx.x * 256 + threadIdx.x;
    if (e >= 520 * cpp) return;
    int pix = e / cpp, ch = e - pix * cpp;
    int r, c;
    if (pix < 131)      { r = 0;   c = pix; }
    else if (pix < 262) { r = 130; c = pix - 131; }
    else { int j = pix - 262; r = 1 + (j >> 1); c = (j & 1) ? 130 : 0; }
    int img = isU ? plane : (plane - 4);
    u16* base = (isU ? U : S1) + ((long)(img * HP + r) * HP + c) * C + ch * 8;
    u32x4 z = {0u, 0u, 0u, 0u};
    *(u32x4*)base = z;
}

// transform weights: Wt[tap][co][ci] (bf16), w3t[c][t] (f32)
__global__ __launch_bounds__(256) void prep_weights(
        const float* __restrict__ wr, const float* __restrict__ w2,
        const float* __restrict__ w3,
        u16* __restrict__ Wt1, u16* __restrict__ Wt2, float* __restrict__ w3t) {
    int i = blockIdx.x * 256 + threadIdx.x;
    if (i < 294912) {
        int tap = i / 32768, r = i & 32767;
        int co = r >> 7, ci = r & 127;
        Wt1[i] = f2bf(wr[(co * 128 + ci) * 9 + tap]);
    } else if (i < 1474560) {
        int j = i - 294912;
        int tap = j / 131072, r = j & 131071;
        int co = r >> 9, ci = r & 511;
        Wt2[j] = f2bf(w2[(co * 512 + ci) * 9 + tap]);
    } else if (i < 1487104) {
        int j = i - 1474560;
        int c = j / 49, t = j - c * 49;
        w3t[j] = w3[t * 256 + c];
    }
}

// bilinear upsample 33x33 -> 129x129, write padded NHWC bf16
__global__ __launch_bounds__(256) void upsample(
        const float* __restrict__ cur, const float* __restrict__ key,
        u16* __restrict__ U) {
    __shared__ float rows[2][128][33];
    const int y = blockIdx.x;
    const int img = blockIdx.y;
    const int frame = img >> 1, bb = img & 1;
    const float* src = (frame ? key : cur) + (long)bb * 128 * 1089;
    const float scale = 33.0f / 129.0f;
    float syf = (y + 0.5f) * scale - 0.5f;
    int sy0 = (int)floorf(syf);
    float wy = syf - (float)sy0;
    int sy0c = sy0 < 0 ? 0 : sy0;
    int sy1c = (sy0 + 1 > 32) ? 32 : sy0 + 1;
    for (int e = threadIdx.x; e < 2 * 128 * 33; e += 256) {
        int rr = e / 4224;
        int rem = e - rr * 4224;
        int c = rem / 33, sx = rem - c * 33;
        rows[rr][c][sx] = src[((long)c * 33 + (rr ? sy1c : sy0c)) * 33 + sx];
    }
    __syncthreads();
    u16* dst = U + ((long)(img * HP + (y + 1)) * HP + 1) * 128;
    for (int e = threadIdx.x; e < 129 * 128; e += 256) {
        int x = e >> 7, c = e & 127;
        float sxf = (x + 0.5f) * scale - 0.5f;
        int sx0 = (int)floorf(sxf);
        float wx = sxf - (float)sx0;
        int sx0c = sx0 < 0 ? 0 : sx0;
        int sx1c = (sx0 + 1 > 32) ? 32 : sx0 + 1;
        float v0 = rows[0][c][sx0c] * (1.f - wx) + rows[0][c][sx1c] * wx;
        float v1 = rows[1][c][sx0c] * (1.f - wx) + rows[1][c][sx1c] * wx;
        dst[(long)x * 128 + c] = f2bf(v0 * (1.f - wy) + v1 * wy);
    }
}

// implicit-GEMM 3x3 conv via MFMA, 128x128 tile, BK=32 — r4 swizzle inner
// loop (verified conflicts = 0). SPLIT=2: split-K into separate bf16 partial
// buffers (bias in half 0, no relu); conv3 combines.
// r5 schedule: 3 LDS buffers, prefetch depth 2, counted s_waitcnt vmcnt(4).
template<int CIN, int MODE, int NWORK, int SPLIT>
__global__ __launch_bounds__(256) void conv_mfma(
        const u16* __restrict__ In, const u16* __restrict__ Wt,
        const float* __restrict__ bias,
        u16* __restrict__ Out0, u16* __restrict__ Out1) {
    constexpr int KC  = CIN / 32;
    constexpr int NS  = 9 * KC;
    constexpr int NSH = NS / SPLIT;
    constexpr int PER = (NWORK + 7) / 8;
    __shared__ u16 As[3][128 * 32];
    __shared__ u16 Bs[3][128 * 32];

    const int id = blockIdx.x;
    const int work = (id & 7) * PER + (id >> 3);
    if (work >= NWORK) return;
    int w = work;
    const int m0 = (w & 1) * 128; w >>= 1;
    int half = 0;
    if (SPLIT == 2) { half = w & 1; w >>= 1; }
    const int xi  = w % 131;
    const int img = w / 131;
    const int p0  = xi * 128;

    const int t    = threadIdx.x;
    const int srow = t >> 2;
    const int scol = ((((t & 3) - (srow >> 1)) & 3) * 8);
    long ub[2];
    #pragma unroll
    for (int is = 0; is < 2; ++is) {
        int p = p0 + srow + is * 64; if (p > NPIX - 1) p = NPIX - 1;
        int y = p / 129, x = p - y * 129;
        ub[is] = ((long)(img * HP + y) * HP + x) * CIN + scol;
    }
    const long wb0 = (long)(m0 + srow) * CIN + scol;

    const int lane = t & 63;
    const int wave = t >> 6;
    const int wm = wave & 1, wn = wave >> 1;
    const int lm = lane & 15, lq = lane >> 4;
    const int koff = (((lq + (lm >> 1)) & 3) * 8);

    auto stage = [&](int s, int buf) {
        const int tap = s / KC;
        const int kc  = (s - tap * KC) * 32;
        const int ky = tap / 3, kx = tap - ky * 3;
        const long toff = (long)(ky * HP + kx) * CIN + kc;
        const u16* WtT = Wt + (long)tap * 256 * CIN + kc;
        char* Aw = (char*)&As[buf][0] + wave * 1024;
        char* Bw = (char*)&Bs[buf][0] + wave * 1024;
        async_cp16(WtT + wb0,             Aw);
        async_cp16(WtT + wb0 + 64L * CIN, Aw + 4096);
        async_cp16(In + ub[0] + toff,     Bw);
        async_cp16(In + ub[1] + toff,     Bw + 4096);
    };

    f32x4 acc[4][4];
    f32x4 zero = {0.f, 0.f, 0.f, 0.f};
    #pragma unroll
    for (int mt = 0; mt < 4; ++mt)
        #pragma unroll
        for (int nt = 0; nt < 4; ++nt) acc[mt][nt] = zero;

    const int s0 = half * NSH;
    stage(s0 + 0, 0);
    stage(s0 + 1, 1);
    #pragma unroll 2
    for (int i = 0; i < NSH; ++i) {
        const int buf = i % 3;
        // counted wait: with <=8 outstanding, vmcnt(4) completes the oldest
        // stage-group = stage(i). Last iter has only stage(NSH-1) in flight.
        if (i < NSH - 1) asm volatile("s_waitcnt vmcnt(4)" ::: "memory");
        else             asm volatile("s_waitcnt vmcnt(0)" ::: "memory");
        __builtin_amdgcn_s_barrier();
        asm volatile("" ::: "memory");
        if (i + 2 < NSH) stage(s0 + i + 2, (i + 2) % 3);
        s16x8 fa[4], fb[4];
        #pragma unroll
        for (int mt = 0; mt < 4; ++mt)
            fa[mt] = *(const s16x8*)&As[buf][(wm * 64 + mt * 16 + lm) * 32 + koff];
        #pragma unroll
        for (int nt = 0; nt < 4; ++nt)
            fb[nt] = *(const s16x8*)&Bs[buf][(wn * 64 + nt * 16 + lm) * 32 + koff];
        #pragma unroll
        for (int mt = 0; mt < 4; ++mt)
            #pragma unroll
            for (int nt = 0; nt < 4; ++nt)
                acc[mt][nt] = __builtin_amdgcn_mfma_f32_16x16x32_bf16(
                    fa[mt], fb[nt], acc[mt][nt], 0, 0, 0);
    }

    u16* OutBf = half ? Out1 : Out0;
    #pragma unroll
    for (int nt = 0; nt < 4; ++nt) {
        int p = p0 + wn * 64 + nt * 16 + lm;
        if (p > NPIX - 1) continue;
        long obase;
        if (MODE == 0) {
            int y = p / 129, x = p - y * 129;
            int bb = img & 1, frame = img >> 1;
            obase = ((long)(bb * HP + (y + 1)) * HP + (x + 1)) * 512 + frame * 256;
        } else {
            obase = ((long)img * NPIX + p) * 256;
        }
        #pragma unroll
        for (int mt = 0; mt < 4; ++mt) {
            int co = m0 + wm * 64 + mt * 16 + lq * 4;
            f32x4 bv = *(const f32x4*)(bias + co);
            if (MODE == 0) {
                float v0 = fmaxf(acc[mt][nt][0] + bv[0], 0.f);
                float v1 = fmaxf(acc[mt][nt][1] + bv[1], 0.f);
                float v2 = fmaxf(acc[mt][nt][2] + bv[2], 0.f);
                float v3 = fmaxf(acc[mt][nt][3] + bv[3], 0.f);
                u16x4 o = { f2bf(v0), f2bf(v1), f2bf(v2), f2bf(v3) };
                *(u16x4*)(OutBf + obase + co) = o;
            } else {
                float bs = half ? 0.f : 1.f;
                u16x4 o = { f2bf(acc[mt][nt][0] + bs * bv[0]),
                            f2bf(acc[mt][nt][1] + bs * bv[1]),
                            f2bf(acc[mt][nt][2] + bs * bv[2]),
                            f2bf(acc[mt][nt][3] + bs * bv[3]) };
                *(u16x4*)(OutBf + obase + co) = o;
            }
        }
    }
}

// pad F (NCHW 129x129) into [2][256][135][136] f32 with 3-px zero halo.
__global__ __launch_bounds__(256) void fpad(
        const float* __restrict__ F, float* __restrict__ Fp) {
    int id = blockIdx.x * 256 + threadIdx.x;
    if (id >= 2 * 256 * FPH * (FPW / 4)) return;
    int ck = id % (FPW / 4);
    int r  = id / (FPW / 4);
    int yy = r % FPH;
    int ch = r / FPH;                       // 0..511 = img*256+c
    int y = yy - 3;
    f32x4 v;
    const float* Fr = F + ((long)ch * 129 + y) * 129;
    #pragma unroll
    for (int j = 0; j < 4; ++j) {
        int x = ck * 4 + j - 3;
        bool in = ((unsigned)x < 129u) && ((unsigned)y < 129u);
        v[j] = in ? Fr[x] : 0.f;
    }
    *(f32x4*)(Fp + (long)ch * FPC + yy * FPW + ck * 4) = v;
}

// combine split-K halves (add, relu) + 1x1 conv (256->49) + softmax.
// 4 threads/pixel (64 ch each), LDS reduce. P written [img][pix][52].
__global__ __launch_bounds__(256) void conv3_softmax(
        const u16* __restrict__ Xa, const u16* __restrict__ Xb,
        const float* __restrict__ W3t, const float* __restrict__ b3,
        float* __restrict__ P) {
    __shared__ float red[3][64][50];
    const int t = threadIdx.x;
    const int pl = t & 63, sub = t >> 6;
    const int idx = blockIdx.x * 64 + pl;
    const bool valid = idx < 2 * NPIX;
    float l[49];
    #pragma unroll
    for (int k = 0; k < 49; ++k) l[k] = 0.f;
    if (valid) {
        const s16x8* xra = (const s16x8*)(Xa + (long)idx * 256 + sub * 64);
        const s16x8* xrb = (const s16x8*)(Xb + (long)idx * 256 + sub * 64);
        #pragma unroll 1
        for (int cb = 0; cb < 8; ++cb) {
            s16x8 av = xra[cb];
            s16x8 bv = xrb[cb];
            #pragma unroll
            for (int j = 0; j < 8; ++j) {
                float xc = fmaxf(bf2f((u16)av[j]) + bf2f((u16)bv[j]), 0.f);
                const float* wrow = W3t + (sub * 64 + cb * 8 + j) * 49;
                #pragma unroll
                for (int k = 0; k < 49; ++k) l[k] = fmaf(wrow[k], xc, l[k]);
            }
        }
    }
    if (sub) {
        #pragma unroll
        for (int k = 0; k < 49; ++k) red[sub - 1][pl][k] = l[k];
    }
    __syncthreads();
    if (!sub && valid) {
        float m = 0.f;
        #pragma unroll
        for (int k = 0; k < 49; ++k) {
            l[k] = fmaxf(l[k] + red[0][pl][k] + red[1][pl][k] + red[2][pl][k]
                         + b3[k], 0.f);
            m = fmaxf(m, l[k]);
        }
        float ssum = 0.f;
        #pragma unroll
        for (int k = 0; k < 49; ++k) { l[k] = __expf(l[k] - m); ssum += l[k]; }
        float inv = 1.f / ssum;
        int bb = idx / NPIX, pix = idx - bb * NPIX;
        float* Pp = P + ((long)bb * NPIX + pix) * 52;
        #pragma unroll
        for (int k = 0; k < 49; ++k) Pp[k] = l[k] * inv;
    }
}

// spatially-variant 7x7 conv v4 (best measured, ~93 µs): vertical pixel-PAIR
// (y even: y and y+1) per thread. 8 row-loads (2x dwordx4 each) feed BOTH
// outputs: 32 F floats per channel-output vs 56 single-pixel. FMA order per
// output: rows asc, taps asc -> matches reference accumulation.
__global__ __launch_bounds__(256) void svconv(
        const float* __restrict__ Fp, const float* __restrict__ P,
        float* __restrict__ Out) {
    const int id = blockIdx.x;
    const int work = (id & 7) * 528 + (id >> 3);   // 4224 total
    const int cg   = work & 63;                    // fastest within XCD span
    const int tile = work >> 6;                    // 0..65
    const int img  = tile / 33, ti = tile % 33;
    const int idx  = ti * 256 + threadIdx.x;       // even-row linear index
    if (idx >= 8385) return;
    const int ry = idx / 129;
    const int y  = 2 * ry;                         // 0,2,...,128
    const int x  = idx - ry * 129;
    const int px0 = y * 129 + x;
    const bool has2 = y < 128;

    float w0[52], w1[52];
    const f32x4* Pp0 = (const f32x4*)(P + ((long)img * NPIX + px0) * 52);
    #pragma unroll
    for (int k = 0; k < 13; ++k) *(f32x4*)&w0[k * 4] = Pp0[k];
    if (has2) {
        const f32x4* Pp1 = (const f32x4*)(P + ((long)img * NPIX + px0 + 129) * 52);
        #pragma unroll
        for (int k = 0; k < 13; ++k) *(f32x4*)&w1[k * 4] = Pp1[k];
    } else {
        #pragma unroll
        for (int k = 0; k < 52; ++k) w1[k] = 0.f;
    }

    const float* Fc0 = Fp + (long)(img * 256 + cg * 4) * FPC + (long)y * FPW + x;
    float a0[4], a1[4];
    #pragma unroll
    for (int c4 = 0; c4 < 4; ++c4) {
        const float* Fc = Fc0 + c4 * FPC;
        float s0 = 0.f, s1 = 0.f;
        #pragma unroll
        for (int r = 0; r < 8; ++r) {              // padded rows y+r
            const float* rp = Fc + r * FPW;
            f32x4u v0 = *(const f32x4u*)rp;
            f32x4u v1 = *(const f32x4u*)(rp + 4);
            if (r < 7) {
                const float* wr = &w0[r * 7];
                s0 = fmaf(wr[0], v0[0], s0);
                s0 = fmaf(wr[1], v0[1], s0);
                s0 = fmaf(wr[2], v0[2], s0);
                s0 = fmaf(wr[3], v0[3], s0);
                s0 = fmaf(wr[4], v1[0], s0);
                s0 = fmaf(wr[5], v1[1], s0);
                s0 = fmaf(wr[6], v1[2], s0);
            }
            if (r > 0) {
                const float* wr = &w1[(r - 1) * 7];
                s1 = fmaf(wr[0], v0[0], s1);
                s1 = fmaf(wr[1], v0[1], s1);
                s1 = fmaf(wr[2], v0[2], s1);
                s1 = fmaf(wr[3], v0[3], s1);
                s1 = fmaf(wr[4], v1[0], s1);
                s1 = fmaf(wr[5], v1[1], s1);
                s1 = fmaf(wr[6], v1[2], s1);
            }
        }
        a0[c4] = s0;
        a1[c4] = s1;
    }
    float* Ob = Out + ((long)(img * 256 + cg * 4)) * NPIX + px0;
    Ob[0]           = a0[0];
    Ob[(long)NPIX]  = a0[1];
    Ob[2L * NPIX]   = a0[2];
    Ob[3L * NPIX]   = a0[3];
    if (has2) {
        float* Ob1 = Ob + 129;
        Ob1[0]          = a1[0];
        Ob1[(long)NPIX] = a1[1];
        Ob1[2L * NPIX]  = a1[2];
        Ob1[3L * NPIX]  = a1[3];
    }
}

extern "C" void kernel_launch(void* const* d_in, const int* in_sizes, int n_in,
                              void* d_out, int out_size, void* d_ws, size_t ws_size,
                              hipStream_t stream) {
    const float* cur      = (const float*)d_in[0];
    const float* key      = (const float*)d_in[1];
    const float* Fhigh    = (const float*)d_in[2];
    const float* w_reduce = (const float*)d_in[3];
    const float* b_reduce = (const float*)d_in[4];
    const float* w_conv2  = (const float*)d_in[5];
    const float* b_conv2  = (const float*)d_in[6];
    const float* w_conv3  = (const float*)d_in[7];
    const float* b_conv3  = (const float*)d_in[8];

    if (ws_size < 89798656UL) return;

    char* ws = (char*)d_ws;
    // phase 1 (through conv2)
    u16*   U     = (u16*)(ws + 0);
    u16*   S1    = (u16*)(ws + 17572864);
    // phase 2 (after conv2; overlays U/S1 region)
    float* Fpad  = (float*)(ws + 0);           // 37,601,280 B
    float* P     = (float*)(ws + 37601280);    //  6,922,656 B
    u16*   Wt1   = (u16*)(ws + 52718592);
    u16*   Wt2   = (u16*)(ws + 53308416);
    u16*   out2a = (u16*)(ws + 55667712);
    u16*   out2b = (u16*)(ws + 72708096);
    float* w3t   = (float*)(ws + 89748480);

    zero_border<<<dim3(130, 6), 256, 0, stream>>>(U, S1);
    prep_weights<<<5809, 256, 0, stream>>>(w_reduce, w_conv2, w_conv3, Wt1, Wt2, w3t);
    upsample<<<dim3(129, 4), 256, 0, stream>>>(cur, key, U);
    conv_mfma<128, 0, 1048, 1><<<1048, 256, 0, stream>>>(U, Wt1, b_reduce, S1, S1);
    conv_mfma<512, 1, 1048, 2><<<1048, 256, 0, stream>>>(S1, Wt2, b_conv2, out2a, out2b);
    fpad<<<9180, 256, 0, stream>>>(Fhigh, Fpad);          // overlays U/S1 (dead)
    conv3_softmax<<<521, 256, 0, stream>>>(out2a, out2b, w3t, b_conv3, P);
    svconv<<<4224, 256, 0, stream>>>(Fpad, P, (float*)d_out);
}

// Round 10
// 446.622 us; speedup vs baseline: 1.7952x; 1.0330x over previous
//
#include <hip/hip_runtime.h>

typedef unsigned short u16;
typedef unsigned int   u32;
typedef __attribute__((ext_vector_type(8))) short s16x8;
typedef __attribute__((ext_vector_type(4))) float f32x4;
typedef __attribute__((ext_vector_type(4), aligned(4))) float f32x4u;  // 4B-aligned vec load
typedef __attribute__((ext_vector_type(4))) u32   u32x4;
typedef __attribute__((ext_vector_type(4))) u16   u16x4;

#define NPIX 16641   /* 129*129 */
#define HP   131     /* padded spatial dim (convs) */
#define FPH  135     /* svconv padded F: height */
#define FPW  136     /* svconv padded F: row stride */
#define FPC  18360   /* FPH*FPW floats per channel */

// ---- workspace layout (bytes) ----
// region A (two lifetimes):
//   phase 1: U [4][131][131][128] bf16 @ 0 (17.6M), S1 [2][131][131][512] bf16 @ 17572864 (35.1M)
//   phase 2 (after conv2): Fpad [2][256][135][136] f32 @ 0 (37,601,280)
//                          P    [2][16641][52] f32     @ 37601280 (6,922,656)
// Wt1  : [9][256][128] bf16  @ 52718592   (589,824)
// Wt2  : [9][256][512] bf16  @ 53308416   (2,359,296)
// out2a: [2*16641][256] bf16 @ 55667712   (17,040,384)  split-K half 0 (pre-relu, +bias)
// out2b: [2*16641][256] bf16 @ 72708096   (17,040,384)  split-K half 1
// w3t  : [256][49] f32       @ 89748480   (50,176)
// total required: 89,798,656 B
//
// CONFIG: conv_mfma r5-schedule (126 µs/conv — structure-matched optimum,
// five structural variants all <=0 with counter-diagnosed causes), fpad +
// svconv v9 (v4 pixel-pair inner loop, 8-ch group per thread: w-loads
// amortized 2x, VMEM/output -13%), conv3_softmax.

__device__ __forceinline__ u16 f2bf(float f) {
    u32 b = __builtin_bit_cast(u32, f);
    return (u16)((b + 0x7fffu + ((b >> 16) & 1u)) >> 16);
}
__device__ __forceinline__ float bf2f(u16 u) {
    return __builtin_bit_cast(float, ((u32)u) << 16);
}

// async global->LDS, 16B per lane; LDS dest wave-uniform base, lane l -> +16*l
__device__ __forceinline__ void async_cp16(const void* g, void* l) {
    __builtin_amdgcn_global_load_lds(
        (const __attribute__((address_space(1))) u32*)g,
        (__attribute__((address_space(3))) u32*)l, 16, 0, 0);
}

// zero only the 1-pixel pad ring of U (4 imgs, C=128) and S1 (2 imgs, C=512).
__global__ __launch_bounds__(256) void zero_border(u16* __restrict__ U,
                                                   u16* __restrict__ S1) {
    const int plane = blockIdx.y;           // 0..3: U, 4..5: S1
    const bool isU = plane < 4;
    const int C = isU ? 128 : 512;
    const int cpp = C / 8;
    int e = blockIdx.x * 256 + threadIdx.x;
    if (e >= 520 * cpp) return;
    int pix = e / cpp, ch = e - pix * cpp;
    int r, c;
    if (pix < 131)      { r = 0;   c = pix; }
    else if (pix < 262) { r = 130; c = pix - 131; }
    else { int j = pix - 262; r = 1 + (j >> 1); c = (j & 1) ? 130 : 0; }
    int img = isU ? plane : (plane - 4);
    u16* base = (isU ? U : S1) + ((long)(img * HP + r) * HP + c) * C + ch * 8;
    u32x4 z = {0u, 0u, 0u, 0u};
    *(u32x4*)base = z;
}

// transform weights: Wt[tap][co][ci] (bf16), w3t[c][t] (f32)
__global__ __launch_bounds__(256) void prep_weights(
        const float* __restrict__ wr, const float* __restrict__ w2,
        const float* __restrict__ w3,
        u16* __restrict__ Wt1, u16* __restrict__ Wt2, float* __restrict__ w3t) {
    int i = blockIdx.x * 256 + threadIdx.x;
    if (i < 294912) {
        int tap = i / 32768, r = i & 32767;
        int co = r >> 7, ci = r & 127;
        Wt1[i] = f2bf(wr[(co * 128 + ci) * 9 + tap]);
    } else if (i < 1474560) {
        int j = i - 294912;
        int tap = j / 131072, r = j & 131071;
        int co = r >> 9, ci = r & 511;
        Wt2[j] = f2bf(w2[(co * 512 + ci) * 9 + tap]);
    } else if (i < 1487104) {
        int j = i - 1474560;
        int c = j / 49, t = j - c * 49;
        w3t[j] = w3[t * 256 + c];
    }
}

// bilinear upsample 33x33 -> 129x129, write padded NHWC bf16
__global__ __launch_bounds__(256) void upsample(
        const float* __restrict__ cur, const float* __restrict__ key,
        u16* __restrict__ U) {
    __shared__ float rows[2][128][33];
    const int y = blockIdx.x;
    const int img = blockIdx.y;
    const int frame = img >> 1, bb = img & 1;
    const float* src = (frame ? key : cur) + (long)bb * 128 * 1089;
    const float scale = 33.0f / 129.0f;
    float syf = (y + 0.5f) * scale - 0.5f;
    int sy0 = (int)floorf(syf);
    float wy = syf - (float)sy0;
    int sy0c = sy0 < 0 ? 0 : sy0;
    int sy1c = (sy0 + 1 > 32) ? 32 : sy0 + 1;
    for (int e = threadIdx.x; e < 2 * 128 * 33; e += 256) {
        int rr = e / 4224;
        int rem = e - rr * 4224;
        int c = rem / 33, sx = rem - c * 33;
        rows[rr][c][sx] = src[((long)c * 33 + (rr ? sy1c : sy0c)) * 33 + sx];
    }
    __syncthreads();
    u16* dst = U + ((long)(img * HP + (y + 1)) * HP + 1) * 128;
    for (int e = threadIdx.x; e < 129 * 128; e += 256) {
        int x = e >> 7, c = e & 127;
        float sxf = (x + 0.5f) * scale - 0.5f;
        int sx0 = (int)floorf(sxf);
        float wx = sxf - (float)sx0;
        int sx0c = sx0 < 0 ? 0 : sx0;
        int sx1c = (sx0 + 1 > 32) ? 32 : sx0 + 1;
        float v0 = rows[0][c][sx0c] * (1.f - wx) + rows[0][c][sx1c] * wx;
        float v1 = rows[1][c][sx0c] * (1.f - wx) + rows[1][c][sx1c] * wx;
        dst[(long)x * 128 + c] = f2bf(v0 * (1.f - wy) + v1 * wy);
    }
}

// implicit-GEMM 3x3 conv via MFMA, 128x128 tile, BK=32 — r4 swizzle inner
// loop (verified conflicts = 0). SPLIT=2: split-K into separate bf16 partial
// buffers (bias in half 0, no relu); conv3 combines.
// r5 schedule: 3 LDS buffers, prefetch depth 2, counted s_waitcnt vmcnt(4).
template<int CIN, int MODE, int NWORK, int SPLIT>
__global__ __launch_bounds__(256) void conv_mfma(
        const u16* __restrict__ In, const u16* __restrict__ Wt,
        const float* __restrict__ bias,
        u16* __restrict__ Out0, u16* __restrict__ Out1) {
    constexpr int KC  = CIN / 32;
    constexpr int NS  = 9 * KC;
    constexpr int NSH = NS / SPLIT;
    constexpr int PER = (NWORK + 7) / 8;
    __shared__ u16 As[3][128 * 32];
    __shared__ u16 Bs[3][128 * 32];

    const int id = blockIdx.x;
    const int work = (id & 7) * PER + (id >> 3);
    if (work >= NWORK) return;
    int w = work;
    const int m0 = (w & 1) * 128; w >>= 1;
    int half = 0;
    if (SPLIT == 2) { half = w & 1; w >>= 1; }
    const int xi  = w % 131;
    const int img = w / 131;
    const int p0  = xi * 128;

    const int t    = threadIdx.x;
    const int srow = t >> 2;
    const int scol = ((((t & 3) - (srow >> 1)) & 3) * 8);
    long ub[2];
    #pragma unroll
    for (int is = 0; is < 2; ++is) {
        int p = p0 + srow + is * 64; if (p > NPIX - 1) p = NPIX - 1;
        int y = p / 129, x = p - y * 129;
        ub[is] = ((long)(img * HP + y) * HP + x) * CIN + scol;
    }
    const long wb0 = (long)(m0 + srow) * CIN + scol;

    const int lane = t & 63;
    const int wave = t >> 6;
    const int wm = wave & 1, wn = wave >> 1;
    const int lm = lane & 15, lq = lane >> 4;
    const int koff = (((lq + (lm >> 1)) & 3) * 8);

    auto stage = [&](int s, int buf) {
        const int tap = s / KC;
        const int kc  = (s - tap * KC) * 32;
        const int ky = tap / 3, kx = tap - ky * 3;
        const long toff = (long)(ky * HP + kx) * CIN + kc;
        const u16* WtT = Wt + (long)tap * 256 * CIN + kc;
        char* Aw = (char*)&As[buf][0] + wave * 1024;
        char* Bw = (char*)&Bs[buf][0] + wave * 1024;
        async_cp16(WtT + wb0,             Aw);
        async_cp16(WtT + wb0 + 64L * CIN, Aw + 4096);
        async_cp16(In + ub[0] + toff,     Bw);
        async_cp16(In + ub[1] + toff,     Bw + 4096);
    };

    f32x4 acc[4][4];
    f32x4 zero = {0.f, 0.f, 0.f, 0.f};
    #pragma unroll
    for (int mt = 0; mt < 4; ++mt)
        #pragma unroll
        for (int nt = 0; nt < 4; ++nt) acc[mt][nt] = zero;

    const int s0 = half * NSH;
    stage(s0 + 0, 0);
    stage(s0 + 1, 1);
    #pragma unroll 2
    for (int i = 0; i < NSH; ++i) {
        const int buf = i % 3;
        // counted wait: with <=8 outstanding, vmcnt(4) completes the oldest
        // stage-group = stage(i). Last iter has only stage(NSH-1) in flight.
        if (i < NSH - 1) asm volatile("s_waitcnt vmcnt(4)" ::: "memory");
        else             asm volatile("s_waitcnt vmcnt(0)" ::: "memory");
        __builtin_amdgcn_s_barrier();
        asm volatile("" ::: "memory");
        if (i + 2 < NSH) stage(s0 + i + 2, (i + 2) % 3);
        s16x8 fa[4], fb[4];
        #pragma unroll
        for (int mt = 0; mt < 4; ++mt)
            fa[mt] = *(const s16x8*)&As[buf][(wm * 64 + mt * 16 + lm) * 32 + koff];
        #pragma unroll
        for (int nt = 0; nt < 4; ++nt)
            fb[nt] = *(const s16x8*)&Bs[buf][(wn * 64 + nt * 16 + lm) * 32 + koff];
        #pragma unroll
        for (int mt = 0; mt < 4; ++mt)
            #pragma unroll
            for (int nt = 0; nt < 4; ++nt)
                acc[mt][nt] = __builtin_amdgcn_mfma_f32_16x16x32_bf16(
                    fa[mt], fb[nt], acc[mt][nt], 0, 0, 0);
    }

    u16* OutBf = half ? Out1 : Out0;
    #pragma unroll
    for (int nt = 0; nt < 4; ++nt) {
        int p = p0 + wn * 64 + nt * 16 + lm;
        if (p > NPIX - 1) continue;
        long obase;
        if (MODE == 0) {
            int y = p / 129, x = p - y * 129;
            int bb = img & 1, frame = img >> 1;
            obase = ((long)(bb * HP + (y + 1)) * HP + (x + 1)) * 512 + frame * 256;
        } else {
            obase = ((long)img * NPIX + p) * 256;
        }
        #pragma unroll
        for (int mt = 0; mt < 4; ++mt) {
            int co = m0 + wm * 64 + mt * 16 + lq * 4;
            f32x4 bv = *(const f32x4*)(bias + co);
            if (MODE == 0) {
                float v0 = fmaxf(acc[mt][nt][0] + bv[0], 0.f);
                float v1 = fmaxf(acc[mt][nt][1] + bv[1], 0.f);
                float v2 = fmaxf(acc[mt][nt][2] + bv[2], 0.f);
                float v3 = fmaxf(acc[mt][nt][3] + bv[3], 0.f);
                u16x4 o = { f2bf(v0), f2bf(v1), f2bf(v2), f2bf(v3) };
                *(u16x4*)(OutBf + obase + co) = o;
            } else {
                float bs = half ? 0.f : 1.f;
                u16x4 o = { f2bf(acc[mt][nt][0] + bs * bv[0]),
                            f2bf(acc[mt][nt][1] + bs * bv[1]),
                            f2bf(acc[mt][nt][2] + bs * bv[2]),
                            f2bf(acc[mt][nt][3] + bs * bv[3]) };
                *(u16x4*)(OutBf + obase + co) = o;
            }
        }
    }
}

// pad F (NCHW 129x129) into [2][256][135][136] f32 with 3-px zero halo.
__global__ __launch_bounds__(256) void fpad(
        const float* __restrict__ F, float* __restrict__ Fp) {
    int id = blockIdx.x * 256 + threadIdx.x;
    if (id >= 2 * 256 * FPH * (FPW / 4)) return;
    int ck = id % (FPW / 4);
    int r  = id / (FPW / 4);
    int yy = r % FPH;
    int ch = r / FPH;                       // 0..511 = img*256+c
    int y = yy - 3;
    f32x4 v;
    const float* Fr = F + ((long)ch * 129 + y) * 129;
    #pragma unroll
    for (int j = 0; j < 4; ++j) {
        int x = ck * 4 + j - 3;
        bool in = ((unsigned)x < 129u) && ((unsigned)y < 129u);
        v[j] = in ? Fr[x] : 0.f;
    }
    *(f32x4*)(Fp + (long)ch * FPC + yy * FPW + ck * 4) = v;
}

// combine split-K halves (add, relu) + 1x1 conv (256->49) + softmax.
// 4 threads/pixel (64 ch each), LDS reduce. P written [img][pix][52].
__global__ __launch_bounds__(256) void conv3_softmax(
        const u16* __restrict__ Xa, const u16* __restrict__ Xb,
        const float* __restrict__ W3t, const float* __restrict__ b3,
        float* __restrict__ P) {
    __shared__ float red[3][64][50];
    const int t = threadIdx.x;
    const int pl = t & 63, sub = t >> 6;
    const int idx = blockIdx.x * 64 + pl;
    const bool valid = idx < 2 * NPIX;
    float l[49];
    #pragma unroll
    for (int k = 0; k < 49; ++k) l[k] = 0.f;
    if (valid) {
        const s16x8* xra = (const s16x8*)(Xa + (long)idx * 256 + sub * 64);
        const s16x8* xrb = (const s16x8*)(Xb + (long)idx * 256 + sub * 64);
        #pragma unroll 1
        for (int cb = 0; cb < 8; ++cb) {
            s16x8 av = xra[cb];
            s16x8 bv = xrb[cb];
            #pragma unroll
            for (int j = 0; j < 8; ++j) {
                float xc = fmaxf(bf2f((u16)av[j]) + bf2f((u16)bv[j]), 0.f);
                const float* wrow = W3t + (sub * 64 + cb * 8 + j) * 49;
                #pragma unroll
                for (int k = 0; k < 49; ++k) l[k] = fmaf(wrow[k], xc, l[k]);
            }
        }
    }
    if (sub) {
        #pragma unroll
        for (int k = 0; k < 49; ++k) red[sub - 1][pl][k] = l[k];
    }
    __syncthreads();
    if (!sub && valid) {
        float m = 0.f;
        #pragma unroll
        for (int k = 0; k < 49; ++k) {
            l[k] = fmaxf(l[k] + red[0][pl][k] + red[1][pl][k] + red[2][pl][k]
                         + b3[k], 0.f);
            m = fmaxf(m, l[k]);
        }
        float ssum = 0.f;
        #pragma unroll
        for (int k = 0; k < 49; ++k) { l[k] = __expf(l[k] - m); ssum += l[k]; }
        float inv = 1.f / ssum;
        int bb = idx / NPIX, pix = idx - bb * NPIX;
        float* Pp = P + ((long)bb * NPIX + pix) * 52;
        #pragma unroll
        for (int k = 0; k < 49; ++k) Pp[k] = l[k] * inv;
    }
}

// spatially-variant 7x7 conv v9: v4's verified pixel-pair inner loop, but
// each thread covers an 8-CHANNEL group via two sequential passes (h=0:
// cg*8..+3, h=1: +4..+7) under #pragma unroll 1 -> register liveness equals
// v4's (a0/a1/f reused per half; w0/w1 already live throughout), while the
// 26 w-loads/thread now serve 16 outputs instead of 8: VMEM per 16 outputs
// 196 -> 170 (-13%) and w-load latency amortizes 2x. FMA order per output
// byte-identical to v4 -> numerics identical. Grid 2112 (32 cg x 66 tiles),
// cg fastest within XCD span (32 blocks sharing P lines on one XCD's L2).
__global__ __launch_bounds__(256) void svconv(
        const float* __restrict__ Fp, const float* __restrict__ P,
        float* __restrict__ Out) {
    const int id = blockIdx.x;
    const int work = (id & 7) * 264 + (id >> 3);   // 2112 total
    const int cg   = work & 31;                    // 8-ch group, fastest
    const int tile = work >> 5;                    // 0..65
    const int img  = tile / 33, ti = tile % 33;
    const int idx  = ti * 256 + threadIdx.x;       // even-row linear index
    if (idx >= 8385) return;
    const int ry = idx / 129;
    const int y  = 2 * ry;                         // 0,2,...,128
    const int x  = idx - ry * 129;
    const int px0 = y * 129 + x;
    const bool has2 = y < 128;

    float w0[52], w1[52];
    const f32x4* Pp0 = (const f32x4*)(P + ((long)img * NPIX + px0) * 52);
    #pragma unroll
    for (int k = 0; k < 13; ++k) *(f32x4*)&w0[k * 4] = Pp0[k];
    if (has2) {
        const f32x4* Pp1 = (const f32x4*)(P + ((long)img * NPIX + px0 + 129) * 52);
        #pragma unroll
        for (int k = 0; k < 13; ++k) *(f32x4*)&w1[k * 4] = Pp1[k];
    } else {
        #pragma unroll
        for (int k = 0; k < 52; ++k) w1[k] = 0.f;
    }

    #pragma unroll 1
    for (int h = 0; h < 2; ++h) {
        const int ch0 = cg * 8 + h * 4;
        const float* Fc0 = Fp + (long)(img * 256 + ch0) * FPC + (long)y * FPW + x;
        float a0[4], a1[4];
        #pragma unroll
        for (int c4 = 0; c4 < 4; ++c4) {
            const float* Fc = Fc0 + c4 * FPC;
            float s0 = 0.f, s1 = 0.f;
            #pragma unroll
            for (int r = 0; r < 8; ++r) {          // padded rows y+r
                const float* rp = Fc + r * FPW;
                f32x4u v0 = *(const f32x4u*)rp;
                f32x4u v1 = *(const f32x4u*)(rp + 4);
                if (r < 7) {
                    const float* wr = &w0[r * 7];
                    s0 = fmaf(wr[0], v0[0], s0);
                    s0 = fmaf(wr[1], v0[1], s0);
                    s0 = fmaf(wr[2], v0[2], s0);
                    s0 = fmaf(wr[3], v0[3], s0);
                    s0 = fmaf(wr[4], v1[0], s0);
                    s0 = fmaf(wr[5], v1[1], s0);
                    s0 = fmaf(wr[6], v1[2], s0);
                }
                if (r > 0) {
                    const float* wr = &w1[(r - 1) * 7];
                    s1 = fmaf(wr[0], v0[0], s1);
                    s1 = fmaf(wr[1], v0[1], s1);
                    s1 = fmaf(wr[2], v0[2], s1);
                    s1 = fmaf(wr[3], v0[3], s1);
                    s1 = fmaf(wr[4], v1[0], s1);
                    s1 = fmaf(wr[5], v1[1], s1);
                    s1 = fmaf(wr[6], v1[2], s1);
                }
            }
            a0[c4] = s0;
            a1[c4] = s1;
        }
        float* Ob = Out + ((long)(img * 256 + ch0)) * NPIX + px0;
        Ob[0]           = a0[0];
        Ob[(long)NPIX]  = a0[1];
        Ob[2L * NPIX]   = a0[2];
        Ob[3L * NPIX]   = a0[3];
        if (has2) {
            float* Ob1 = Ob + 129;
            Ob1[0]          = a1[0];
            Ob1[(long)NPIX] = a1[1];
            Ob1[2L * NPIX]  = a1[2];
            Ob1[3L * NPIX]  = a1[3];
        }
    }
}

extern "C" void kernel_launch(void* const* d_in, const int* in_sizes, int n_in,
                              void* d_out, int out_size, void* d_ws, size_t ws_size,
                              hipStream_t stream) {
    const float* cur      = (const float*)d_in[0];
    const float* key      = (const float*)d_in[1];
    const float* Fhigh    = (const float*)d_in[2];
    const float* w_reduce = (const float*)d_in[3];
    const float* b_reduce = (const float*)d_in[4];
    const float* w_conv2  = (const float*)d_in[5];
    const float* b_conv2  = (const float*)d_in[6];
    const float* w_conv3  = (const float*)d_in[7];
    const float* b_conv3  = (const float*)d_in[8];

    if (ws_size < 89798656UL) return;

    char* ws = (char*)d_ws;
    // phase 1 (through conv2)
    u16*   U     = (u16*)(ws + 0);
    u16*   S1    = (u16*)(ws + 17572864);
    // phase 2 (after conv2; overlays U/S1 region)
    float* Fpad  = (float*)(ws + 0);           // 37,601,280 B
    float* P     = (float*)(ws + 37601280);    //  6,922,656 B
    u16*   Wt1   = (u16*)(ws + 52718592);
    u16*   Wt2   = (u16*)(ws + 53308416);
    u16*   out2a = (u16*)(ws + 55667712);
    u16*   out2b = (u16*)(ws + 72708096);
    float* w3t   = (float*)(ws + 89748480);

    zero_border<<<dim3(130, 6), 256, 0, stream>>>(U, S1);
    prep_weights<<<5809, 256, 0, stream>>>(w_reduce, w_conv2, w_conv3, Wt1, Wt2, w3t);
    upsample<<<dim3(129, 4), 256, 0, stream>>>(cur, key, U);
    conv_mfma<128, 0, 1048, 1><<<1048, 256, 0, stream>>>(U, Wt1, b_reduce, S1, S1);
    conv_mfma<512, 1, 1048, 2><<<1048, 256, 0, stream>>>(S1, Wt2, b_conv2, out2a, out2b);
    fpad<<<9180, 256, 0, stream>>>(Fhigh, Fpad);          // overlays U/S1 (dead)
    conv3_softmax<<<521, 256, 0, stream>>>(out2a, out2b, w3t, b_conv3, P);
    svconv<<<2112, 256, 0, stream>>>(Fpad, P, (float*)d_out);
}

// Round 11
// 436.951 us; speedup vs baseline: 1.8350x; 1.0221x over previous
//
#include <hip/hip_runtime.h>

typedef unsigned short u16;
typedef unsigned int   u32;
typedef __attribute__((ext_vector_type(8))) short s16x8;
typedef __attribute__((ext_vector_type(4))) float f32x4;
typedef __attribute__((ext_vector_type(4), aligned(4))) float f32x4u;  // 4B-aligned vec load
typedef __attribute__((ext_vector_type(4))) u32   u32x4;
typedef __attribute__((ext_vector_type(4))) u16   u16x4;

#define NPIX 16641   /* 129*129 */
#define HP   131     /* padded spatial dim (convs) */
#define FPH  135     /* svconv padded F: height */
#define FPW  136     /* svconv padded F: row stride */
#define FPC  18360   /* FPH*FPW floats per channel */

// ---- workspace layout (bytes) ----
// region A (two lifetimes):
//   phase 1: U [4][131][131][128] bf16 @ 0 (17.6M), S1 [2][131][131][512] bf16 @ 17572864 (35.1M)
//   phase 2 (after conv2): Fpad [2][256][135][136] f32 @ 0 (37,601,280)
//                          P    [2][16641][52] f32     @ 37601280 (6,922,656)
// Wt1  : [9][256][128] bf16  @ 52718592   (589,824)
// Wt2  : [9][256][512] bf16  @ 53308416   (2,359,296)
// out2a: [2*16641][256] bf16 @ 55667712   (17,040,384)  split-K half 0 (pre-relu, +bias)
// out2b: [2*16641][256] bf16 @ 72708096   (17,040,384)  split-K half 1
// w3t  : [256][49] f32       @ 89748480   (50,176)
// total required: 89,798,656 B
//
// CONFIG: conv_mfma r5-schedule (126 µs/conv — structure-matched optimum,
// five structural variants all <=0 with counter-diagnosed causes), fpad +
// svconv v10 (v4 pixel-pair inner loop, 16-ch group per thread: w-loads
// amortized 4x, VMEM/16-outputs 196->157), conv3_softmax.

__device__ __forceinline__ u16 f2bf(float f) {
    u32 b = __builtin_bit_cast(u32, f);
    return (u16)((b + 0x7fffu + ((b >> 16) & 1u)) >> 16);
}
__device__ __forceinline__ float bf2f(u16 u) {
    return __builtin_bit_cast(float, ((u32)u) << 16);
}

// async global->LDS, 16B per lane; LDS dest wave-uniform base, lane l -> +16*l
__device__ __forceinline__ void async_cp16(const void* g, void* l) {
    __builtin_amdgcn_global_load_lds(
        (const __attribute__((address_space(1))) u32*)g,
        (__attribute__((address_space(3))) u32*)l, 16, 0, 0);
}

// zero only the 1-pixel pad ring of U (4 imgs, C=128) and S1 (2 imgs, C=512).
__global__ __launch_bounds__(256) void zero_border(u16* __restrict__ U,
                                                   u16* __restrict__ S1) {
    const int plane = blockIdx.y;           // 0..3: U, 4..5: S1
    const bool isU = plane < 4;
    const int C = isU ? 128 : 512;
    const int cpp = C / 8;
    int e = blockIdx.x * 256 + threadIdx.x;
    if (e >= 520 * cpp) return;
    int pix = e / cpp, ch = e - pix * cpp;
    int r, c;
    if (pix < 131)      { r = 0;   c = pix; }
    else if (pix < 262) { r = 130; c = pix - 131; }
    else { int j = pix - 262; r = 1 + (j >> 1); c = (j & 1) ? 130 : 0; }
    int img = isU ? plane : (plane - 4);
    u16* base = (isU ? U : S1) + ((long)(img * HP + r) * HP + c) * C + ch * 8;
    u32x4 z = {0u, 0u, 0u, 0u};
    *(u32x4*)base = z;
}

// transform weights: Wt[tap][co][ci] (bf16), w3t[c][t] (f32)
__global__ __launch_bounds__(256) void prep_weights(
        const float* __restrict__ wr, const float* __restrict__ w2,
        const float* __restrict__ w3,
        u16* __restrict__ Wt1, u16* __restrict__ Wt2, float* __restrict__ w3t) {
    int i = blockIdx.x * 256 + threadIdx.x;
    if (i < 294912) {
        int tap = i / 32768, r = i & 32767;
        int co = r >> 7, ci = r & 127;
        Wt1[i] = f2bf(wr[(co * 128 + ci) * 9 + tap]);
    } else if (i < 1474560) {
        int j = i - 294912;
        int tap = j / 131072, r = j & 131071;
        int co = r >> 9, ci = r & 511;
        Wt2[j] = f2bf(w2[(co * 512 + ci) * 9 + tap]);
    } else if (i < 1487104) {
        int j = i - 1474560;
        int c = j / 49, t = j - c * 49;
        w3t[j] = w3[t * 256 + c];
    }
}

// bilinear upsample 33x33 -> 129x129, write padded NHWC bf16
__global__ __launch_bounds__(256) void upsample(
        const float* __restrict__ cur, const float* __restrict__ key,
        u16* __restrict__ U) {
    __shared__ float rows[2][128][33];
    const int y = blockIdx.x;
    const int img = blockIdx.y;
    const int frame = img >> 1, bb = img & 1;
    const float* src = (frame ? key : cur) + (long)bb * 128 * 1089;
    const float scale = 33.0f / 129.0f;
    float syf = (y + 0.5f) * scale - 0.5f;
    int sy0 = (int)floorf(syf);
    float wy = syf - (float)sy0;
    int sy0c = sy0 < 0 ? 0 : sy0;
    int sy1c = (sy0 + 1 > 32) ? 32 : sy0 + 1;
    for (int e = threadIdx.x; e < 2 * 128 * 33; e += 256) {
        int rr = e / 4224;
        int rem = e - rr * 4224;
        int c = rem / 33, sx = rem - c * 33;
        rows[rr][c][sx] = src[((long)c * 33 + (rr ? sy1c : sy0c)) * 33 + sx];
    }
    __syncthreads();
    u16* dst = U + ((long)(img * HP + (y + 1)) * HP + 1) * 128;
    for (int e = threadIdx.x; e < 129 * 128; e += 256) {
        int x = e >> 7, c = e & 127;
        float sxf = (x + 0.5f) * scale - 0.5f;
        int sx0 = (int)floorf(sxf);
        float wx = sxf - (float)sx0;
        int sx0c = sx0 < 0 ? 0 : sx0;
        int sx1c = (sx0 + 1 > 32) ? 32 : sx0 + 1;
        float v0 = rows[0][c][sx0c] * (1.f - wx) + rows[0][c][sx1c] * wx;
        float v1 = rows[1][c][sx0c] * (1.f - wx) + rows[1][c][sx1c] * wx;
        dst[(long)x * 128 + c] = f2bf(v0 * (1.f - wy) + v1 * wy);
    }
}

// implicit-GEMM 3x3 conv via MFMA, 128x128 tile, BK=32 — r4 swizzle inner
// loop (verified conflicts = 0). SPLIT=2: split-K into separate bf16 partial
// buffers (bias in half 0, no relu); conv3 combines.
// r5 schedule: 3 LDS buffers, prefetch depth 2, counted s_waitcnt vmcnt(4).
template<int CIN, int MODE, int NWORK, int SPLIT>
__global__ __launch_bounds__(256) void conv_mfma(
        const u16* __restrict__ In, const u16* __restrict__ Wt,
        const float* __restrict__ bias,
        u16* __restrict__ Out0, u16* __restrict__ Out1) {
    constexpr int KC  = CIN / 32;
    constexpr int NS  = 9 * KC;
    constexpr int NSH = NS / SPLIT;
    constexpr int PER = (NWORK + 7) / 8;
    __shared__ u16 As[3][128 * 32];
    __shared__ u16 Bs[3][128 * 32];

    const int id = blockIdx.x;
    const int work = (id & 7) * PER + (id >> 3);
    if (work >= NWORK) return;
    int w = work;
    const int m0 = (w & 1) * 128; w >>= 1;
    int half = 0;
    if (SPLIT == 2) { half = w & 1; w >>= 1; }
    const int xi  = w % 131;
    const int img = w / 131;
    const int p0  = xi * 128;

    const int t    = threadIdx.x;
    const int srow = t >> 2;
    const int scol = ((((t & 3) - (srow >> 1)) & 3) * 8);
    long ub[2];
    #pragma unroll
    for (int is = 0; is < 2; ++is) {
        int p = p0 + srow + is * 64; if (p > NPIX - 1) p = NPIX - 1;
        int y = p / 129, x = p - y * 129;
        ub[is] = ((long)(img * HP + y) * HP + x) * CIN + scol;
    }
    const long wb0 = (long)(m0 + srow) * CIN + scol;

    const int lane = t & 63;
    const int wave = t >> 6;
    const int wm = wave & 1, wn = wave >> 1;
    const int lm = lane & 15, lq = lane >> 4;
    const int koff = (((lq + (lm >> 1)) & 3) * 8);

    auto stage = [&](int s, int buf) {
        const int tap = s / KC;
        const int kc  = (s - tap * KC) * 32;
        const int ky = tap / 3, kx = tap - ky * 3;
        const long toff = (long)(ky * HP + kx) * CIN + kc;
        const u16* WtT = Wt + (long)tap * 256 * CIN + kc;
        char* Aw = (char*)&As[buf][0] + wave * 1024;
        char* Bw = (char*)&Bs[buf][0] + wave * 1024;
        async_cp16(WtT + wb0,             Aw);
        async_cp16(WtT + wb0 + 64L * CIN, Aw + 4096);
        async_cp16(In + ub[0] + toff,     Bw);
        async_cp16(In + ub[1] + toff,     Bw + 4096);
    };

    f32x4 acc[4][4];
    f32x4 zero = {0.f, 0.f, 0.f, 0.f};
    #pragma unroll
    for (int mt = 0; mt < 4; ++mt)
        #pragma unroll
        for (int nt = 0; nt < 4; ++nt) acc[mt][nt] = zero;

    const int s0 = half * NSH;
    stage(s0 + 0, 0);
    stage(s0 + 1, 1);
    #pragma unroll 2
    for (int i = 0; i < NSH; ++i) {
        const int buf = i % 3;
        // counted wait: with <=8 outstanding, vmcnt(4) completes the oldest
        // stage-group = stage(i). Last iter has only stage(NSH-1) in flight.
        if (i < NSH - 1) asm volatile("s_waitcnt vmcnt(4)" ::: "memory");
        else             asm volatile("s_waitcnt vmcnt(0)" ::: "memory");
        __builtin_amdgcn_s_barrier();
        asm volatile("" ::: "memory");
        if (i + 2 < NSH) stage(s0 + i + 2, (i + 2) % 3);
        s16x8 fa[4], fb[4];
        #pragma unroll
        for (int mt = 0; mt < 4; ++mt)
            fa[mt] = *(const s16x8*)&As[buf][(wm * 64 + mt * 16 + lm) * 32 + koff];
        #pragma unroll
        for (int nt = 0; nt < 4; ++nt)
            fb[nt] = *(const s16x8*)&Bs[buf][(wn * 64 + nt * 16 + lm) * 32 + koff];
        #pragma unroll
        for (int mt = 0; mt < 4; ++mt)
            #pragma unroll
            for (int nt = 0; nt < 4; ++nt)
                acc[mt][nt] = __builtin_amdgcn_mfma_f32_16x16x32_bf16(
                    fa[mt], fb[nt], acc[mt][nt], 0, 0, 0);
    }

    u16* OutBf = half ? Out1 : Out0;
    #pragma unroll
    for (int nt = 0; nt < 4; ++nt) {
        int p = p0 + wn * 64 + nt * 16 + lm;
        if (p > NPIX - 1) continue;
        long obase;
        if (MODE == 0) {
            int y = p / 129, x = p - y * 129;
            int bb = img & 1, frame = img >> 1;
            obase = ((long)(bb * HP + (y + 1)) * HP + (x + 1)) * 512 + frame * 256;
        } else {
            obase = ((long)img * NPIX + p) * 256;
        }
        #pragma unroll
        for (int mt = 0; mt < 4; ++mt) {
            int co = m0 + wm * 64 + mt * 16 + lq * 4;
            f32x4 bv = *(const f32x4*)(bias + co);
            if (MODE == 0) {
                float v0 = fmaxf(acc[mt][nt][0] + bv[0], 0.f);
                float v1 = fmaxf(acc[mt][nt][1] + bv[1], 0.f);
                float v2 = fmaxf(acc[mt][nt][2] + bv[2], 0.f);
                float v3 = fmaxf(acc[mt][nt][3] + bv[3], 0.f);
                u16x4 o = { f2bf(v0), f2bf(v1), f2bf(v2), f2bf(v3) };
                *(u16x4*)(OutBf + obase + co) = o;
            } else {
                float bs = half ? 0.f : 1.f;
                u16x4 o = { f2bf(acc[mt][nt][0] + bs * bv[0]),
                            f2bf(acc[mt][nt][1] + bs * bv[1]),
                            f2bf(acc[mt][nt][2] + bs * bv[2]),
                            f2bf(acc[mt][nt][3] + bs * bv[3]) };
                *(u16x4*)(OutBf + obase + co) = o;
            }
        }
    }
}

// pad F (NCHW 129x129) into [2][256][135][136] f32 with 3-px zero halo.
__global__ __launch_bounds__(256) void fpad(
        const float* __restrict__ F, float* __restrict__ Fp) {
    int id = blockIdx.x * 256 + threadIdx.x;
    if (id >= 2 * 256 * FPH * (FPW / 4)) return;
    int ck = id % (FPW / 4);
    int r  = id / (FPW / 4);
    int yy = r % FPH;
    int ch = r / FPH;                       // 0..511 = img*256+c
    int y = yy - 3;
    f32x4 v;
    const float* Fr = F + ((long)ch * 129 + y) * 129;
    #pragma unroll
    for (int j = 0; j < 4; ++j) {
        int x = ck * 4 + j - 3;
        bool in = ((unsigned)x < 129u) && ((unsigned)y < 129u);
        v[j] = in ? Fr[x] : 0.f;
    }
    *(f32x4*)(Fp + (long)ch * FPC + yy * FPW + ck * 4) = v;
}

// combine split-K halves (add, relu) + 1x1 conv (256->49) + softmax.
// 4 threads/pixel (64 ch each), LDS reduce. P written [img][pix][52].
__global__ __launch_bounds__(256) void conv3_softmax(
        const u16* __restrict__ Xa, const u16* __restrict__ Xb,
        const float* __restrict__ W3t, const float* __restrict__ b3,
        float* __restrict__ P) {
    __shared__ float red[3][64][50];
    const int t = threadIdx.x;
    const int pl = t & 63, sub = t >> 6;
    const int idx = blockIdx.x * 64 + pl;
    const bool valid = idx < 2 * NPIX;
    float l[49];
    #pragma unroll
    for (int k = 0; k < 49; ++k) l[k] = 0.f;
    if (valid) {
        const s16x8* xra = (const s16x8*)(Xa + (long)idx * 256 + sub * 64);
        const s16x8* xrb = (const s16x8*)(Xb + (long)idx * 256 + sub * 64);
        #pragma unroll 1
        for (int cb = 0; cb < 8; ++cb) {
            s16x8 av = xra[cb];
            s16x8 bv = xrb[cb];
            #pragma unroll
            for (int j = 0; j < 8; ++j) {
                float xc = fmaxf(bf2f((u16)av[j]) + bf2f((u16)bv[j]), 0.f);
                const float* wrow = W3t + (sub * 64 + cb * 8 + j) * 49;
                #pragma unroll
                for (int k = 0; k < 49; ++k) l[k] = fmaf(wrow[k], xc, l[k]);
            }
        }
    }
    if (sub) {
        #pragma unroll
        for (int k = 0; k < 49; ++k) red[sub - 1][pl][k] = l[k];
    }
    __syncthreads();
    if (!sub && valid) {
        float m = 0.f;
        #pragma unroll
        for (int k = 0; k < 49; ++k) {
            l[k] = fmaxf(l[k] + red[0][pl][k] + red[1][pl][k] + red[2][pl][k]
                         + b3[k], 0.f);
            m = fmaxf(m, l[k]);
        }
        float ssum = 0.f;
        #pragma unroll
        for (int k = 0; k < 49; ++k) { l[k] = __expf(l[k] - m); ssum += l[k]; }
        float inv = 1.f / ssum;
        int bb = idx / NPIX, pix = idx - bb * NPIX;
        float* Pp = P + ((long)bb * NPIX + pix) * 52;
        #pragma unroll
        for (int k = 0; k < 49; ++k) Pp[k] = l[k] * inv;
    }
}

// spatially-variant 7x7 conv v10: v9 with the channel group widened to 16
// (4 sequential passes h=0..3, ch0 = cg*16 + h*4) under #pragma unroll 1.
// Register liveness equals v4/v9 (a0/a1/f reused per pass; w0/w1 live
// throughout), while the 26 w-loads/thread now serve 32 outputs: VMEM per
// 16 outputs 196(v4) -> 170(v9) -> 157, w-load latency amortized 4x.
// v9 measured: -15 µs vs v4 (matched prediction). FMA order per output
// byte-identical to v4 -> numerics identical. Grid 1056 (16 cg x 66 tiles,
// ~4 blocks/CU = 16 waves/CU); cg fastest within XCD span so the 16 blocks
// sharing a pixel-tile's P lines hit one XCD's L2.
__global__ __launch_bounds__(256) void svconv(
        const float* __restrict__ Fp, const float* __restrict__ P,
        float* __restrict__ Out) {
    const int id = blockIdx.x;
    const int work = (id & 7) * 132 + (id >> 3);   // 1056 total
    const int cg   = work & 15;                    // 16-ch group, fastest
    const int tile = work >> 4;                    // 0..65
    const int img  = tile / 33, ti = tile % 33;
    const int idx  = ti * 256 + threadIdx.x;       // even-row linear index
    if (idx >= 8385) return;
    const int ry = idx / 129;
    const int y  = 2 * ry;                         // 0,2,...,128
    const int x  = idx - ry * 129;
    const int px0 = y * 129 + x;
    const bool has2 = y < 128;

    float w0[52], w1[52];
    const f32x4* Pp0 = (const f32x4*)(P + ((long)img * NPIX + px0) * 52);
    #pragma unroll
    for (int k = 0; k < 13; ++k) *(f32x4*)&w0[k * 4] = Pp0[k];
    if (has2) {
        const f32x4* Pp1 = (const f32x4*)(P + ((long)img * NPIX + px0 + 129) * 52);
        #pragma unroll
        for (int k = 0; k < 13; ++k) *(f32x4*)&w1[k * 4] = Pp1[k];
    } else {
        #pragma unroll
        for (int k = 0; k < 52; ++k) w1[k] = 0.f;
    }

    #pragma unroll 1
    for (int h = 0; h < 4; ++h) {
        const int ch0 = cg * 16 + h * 4;
        const float* Fc0 = Fp + (long)(img * 256 + ch0) * FPC + (long)y * FPW + x;
        float a0[4], a1[4];
        #pragma unroll
        for (int c4 = 0; c4 < 4; ++c4) {
            const float* Fc = Fc0 + c4 * FPC;
            float s0 = 0.f, s1 = 0.f;
            #pragma unroll
            for (int r = 0; r < 8; ++r) {          // padded rows y+r
                const float* rp = Fc + r * FPW;
                f32x4u v0 = *(const f32x4u*)rp;
                f32x4u v1 = *(const f32x4u*)(rp + 4);
                if (r < 7) {
                    const float* wr = &w0[r * 7];
                    s0 = fmaf(wr[0], v0[0], s0);
                    s0 = fmaf(wr[1], v0[1], s0);
                    s0 = fmaf(wr[2], v0[2], s0);
                    s0 = fmaf(wr[3], v0[3], s0);
                    s0 = fmaf(wr[4], v1[0], s0);
                    s0 = fmaf(wr[5], v1[1], s0);
                    s0 = fmaf(wr[6], v1[2], s0);
                }
                if (r > 0) {
                    const float* wr = &w1[(r - 1) * 7];
                    s1 = fmaf(wr[0], v0[0], s1);
                    s1 = fmaf(wr[1], v0[1], s1);
                    s1 = fmaf(wr[2], v0[2], s1);
                    s1 = fmaf(wr[3], v0[3], s1);
                    s1 = fmaf(wr[4], v1[0], s1);
                    s1 = fmaf(wr[5], v1[1], s1);
                    s1 = fmaf(wr[6], v1[2], s1);
                }
            }
            a0[c4] = s0;
            a1[c4] = s1;
        }
        float* Ob = Out + ((long)(img * 256 + ch0)) * NPIX + px0;
        Ob[0]           = a0[0];
        Ob[(long)NPIX]  = a0[1];
        Ob[2L * NPIX]   = a0[2];
        Ob[3L * NPIX]   = a0[3];
        if (has2) {
            float* Ob1 = Ob + 129;
            Ob1[0]          = a1[0];
            Ob1[(long)NPIX] = a1[1];
            Ob1[2L * NPIX]  = a1[2];
            Ob1[3L * NPIX]  = a1[3];
        }
    }
}

extern "C" void kernel_launch(void* const* d_in, const int* in_sizes, int n_in,
                              void* d_out, int out_size, void* d_ws, size_t ws_size,
                              hipStream_t stream) {
    const float* cur      = (const float*)d_in[0];
    const float* key      = (const float*)d_in[1];
    const float* Fhigh    = (const float*)d_in[2];
    const float* w_reduce = (const float*)d_in[3];
    const float* b_reduce = (const float*)d_in[4];
    const float* w_conv2  = (const float*)d_in[5];
    const float* b_conv2  = (const float*)d_in[6];
    const float* w_conv3  = (const float*)d_in[7];
    const float* b_conv3  = (const float*)d_in[8];

    if (ws_size < 89798656UL) return;

    char* ws = (char*)d_ws;
    // phase 1 (through conv2)
    u16*   U     = (u16*)(ws + 0);
    u16*   S1    = (u16*)(ws + 17572864);
    // phase 2 (after conv2; overlays U/S1 region)
    float* Fpad  = (float*)(ws + 0);           // 37,601,280 B
    float* P     = (float*)(ws + 37601280);    //  6,922,656 B
    u16*   Wt1   = (u16*)(ws + 52718592);
    u16*   Wt2   = (u16*)(ws + 53308416);
    u16*   out2a = (u16*)(ws + 55667712);
    u16*   out2b = (u16*)(ws + 72708096);
    float* w3t   = (float*)(ws + 89748480);

    zero_border<<<dim3(130, 6), 256, 0, stream>>>(U, S1);
    prep_weights<<<5809, 256, 0, stream>>>(w_reduce, w_conv2, w_conv3, Wt1, Wt2, w3t);
    upsample<<<dim3(129, 4), 256, 0, stream>>>(cur, key, U);
    conv_mfma<128, 0, 1048, 1><<<1048, 256, 0, stream>>>(U, Wt1, b_reduce, S1, S1);
    conv_mfma<512, 1, 1048, 2><<<1048, 256, 0, stream>>>(S1, Wt2, b_conv2, out2a, out2b);
    fpad<<<9180, 256, 0, stream>>>(Fhigh, Fpad);          // overlays U/S1 (dead)
    conv3_softmax<<<521, 256, 0, stream>>>(out2a, out2b, w3t, b_conv3, P);
    svconv<<<1056, 256, 0, stream>>>(Fpad, P, (float*)d_out);
}